// Round 1
// baseline (1915.252 us; speedup 1.0000x reference)
//
#include <hip/hip_runtime.h>

#define S_TOK 32768
#define DIN   2048
#define NH    8
#define NG    4
#define DH    128
#define NSINK 16
#define BK    64

typedef float        f32x4 __attribute__((ext_vector_type(4)));
typedef short        s16x8 __attribute__((ext_vector_type(8)));
typedef unsigned int u32x4 __attribute__((ext_vector_type(4)));
typedef unsigned int u32x2 __attribute__((ext_vector_type(2)));

__device__ __forceinline__ unsigned short f2bf(float f) {
    unsigned int u = __builtin_bit_cast(unsigned int, f);
    u = (u + 0x7fffu + ((u >> 16) & 1u)) >> 16;
    return (unsigned short)u;
}
__device__ __forceinline__ float bf2f(unsigned short h) {
    unsigned int u = ((unsigned int)h) << 16;
    return __builtin_bit_cast(float, u);
}
__device__ __forceinline__ unsigned int pack2(float lo, float hi) {
    return (unsigned int)f2bf(lo) | ((unsigned int)f2bf(hi) << 16);
}

// ---------------- Kernel A: k = RMSNorm(hidden @ Wk^T) * k_norm_w -> ws bf16 [S][1024]
__global__ __launch_bounds__(256) void kproj_kernel(const float* __restrict__ hid,
                                                    const float* __restrict__ Wk,
                                                    const float* __restrict__ knw,
                                                    unsigned short* __restrict__ kn_ws)
{
    __shared__ alignas(16) char smem[36864];
    __shared__ float rms_l[128];
    __shared__ float wsm[128];
    unsigned short (*As)[72]  = (unsigned short(*)[72])smem;
    unsigned short (*Bs)[72]  = (unsigned short(*)[72])(smem + 18432);
    unsigned short (*qs)[132] = (unsigned short(*)[132])smem;   // aliases As/Bs after GEMM

    const int tid  = threadIdx.x;
    const int lane = tid & 63;
    const int wv   = tid >> 6;
    const int wm   = wv >> 1, wn = wv & 1;
    const int m0   = blockIdx.x * 128;
    const int h    = blockIdx.y;

    if (tid < 128) wsm[tid] = knw[tid];

    const float* Ab = hid + (size_t)m0 * DIN;
    const float* Bb = Wk + (size_t)h * DH * DIN;

    f32x4 acc[4][4];
#pragma unroll
    for (int m = 0; m < 4; ++m)
#pragma unroll
        for (int n = 0; n < 4; ++n)
            acc[m][n] = f32x4{0.f, 0.f, 0.f, 0.f};

    const int r0 = tid >> 3;
    const int c0 = (tid & 7) * 8;
    for (int kt = 0; kt < DIN; kt += BK) {
        __syncthreads();
#pragma unroll
        for (int rr = 0; rr < 4; ++rr) {
            const int r = r0 + rr * 32;
            const float* p = Ab + (size_t)r * DIN + kt + c0;
            float4 x = *(const float4*)p;
            float4 y = *(const float4*)(p + 4);
            u32x4 v; v.x = pack2(x.x, x.y); v.y = pack2(x.z, x.w);
            v.z = pack2(y.x, y.y); v.w = pack2(y.z, y.w);
            *(u32x4*)&As[r][c0] = v;
            p = Bb + (size_t)r * DIN + kt + c0;
            x = *(const float4*)p;
            y = *(const float4*)(p + 4);
            v.x = pack2(x.x, x.y); v.y = pack2(x.z, x.w);
            v.z = pack2(y.x, y.y); v.w = pack2(y.z, y.w);
            *(u32x4*)&Bs[r][c0] = v;
        }
        __syncthreads();
#pragma unroll
        for (int kk = 0; kk < 2; ++kk) {
            s16x8 af[4], bfr[4];
#pragma unroll
            for (int m = 0; m < 4; ++m)
                af[m] = *(const s16x8*)&As[wm * 64 + m * 16 + (lane & 15)][kk * 32 + (lane >> 4) * 8];
#pragma unroll
            for (int n = 0; n < 4; ++n)
                bfr[n] = *(const s16x8*)&Bs[wn * 64 + n * 16 + (lane & 15)][kk * 32 + (lane >> 4) * 8];
#pragma unroll
            for (int m = 0; m < 4; ++m)
#pragma unroll
                for (int n = 0; n < 4; ++n)
                    acc[m][n] = __builtin_amdgcn_mfma_f32_16x16x32_bf16(af[m], bfr[n], acc[m][n], 0, 0, 0);
        }
    }
    __syncthreads();
    // acc -> qs (k_raw, bf16). C layout: col = lane&15, row = (lane>>4)*4 + reg.
#pragma unroll
    for (int m = 0; m < 4; ++m)
#pragma unroll
        for (int n = 0; n < 4; ++n)
#pragma unroll
            for (int r = 0; r < 4; ++r)
                qs[wm * 64 + m * 16 + (lane >> 4) * 4 + r][wn * 64 + n * 16 + (lane & 15)] = f2bf(acc[m][n][r]);
    __syncthreads();
    if (tid < 128) {
        const unsigned short* row = qs[tid];
        float s2 = 0.f;
#pragma unroll 4
        for (int dw = 0; dw < 64; ++dw) {
            unsigned int v = *(const unsigned int*)&row[dw * 2];
            float f0 = bf2f((unsigned short)(v & 0xffff));
            float f1 = bf2f((unsigned short)(v >> 16));
            s2 += f0 * f0 + f1 * f1;
        }
        rms_l[tid] = rsqrtf(s2 * (1.0f / 128.0f) + 1e-6f);
    }
    __syncthreads();
    const int rloc = tid >> 4, cb = (tid & 15) * 8;
#pragma unroll
    for (int pass = 0; pass < 8; ++pass) {
        const int r = pass * 16 + rloc;
        const float rq = rms_l[r];
        u32x4 v;
        float f0, f1;
        f0 = bf2f(qs[r][cb + 0]) * rq * wsm[cb + 0];
        f1 = bf2f(qs[r][cb + 1]) * rq * wsm[cb + 1];
        v.x = pack2(f0, f1);
        f0 = bf2f(qs[r][cb + 2]) * rq * wsm[cb + 2];
        f1 = bf2f(qs[r][cb + 3]) * rq * wsm[cb + 3];
        v.y = pack2(f0, f1);
        f0 = bf2f(qs[r][cb + 4]) * rq * wsm[cb + 4];
        f1 = bf2f(qs[r][cb + 5]) * rq * wsm[cb + 5];
        v.z = pack2(f0, f1);
        f0 = bf2f(qs[r][cb + 6]) * rq * wsm[cb + 6];
        f1 = bf2f(qs[r][cb + 7]) * rq * wsm[cb + 7];
        v.w = pack2(f0, f1);
        *(u32x4*)&kn_ws[(size_t)(m0 + r) * (NH * DH) + h * DH + cb] = v;
    }
}

// ---------------- Kernel B: q-proj + RMSNorm + sink-gate score, atomicAdd into out
__global__ __launch_bounds__(256) void qscore_kernel(const float* __restrict__ hid,
                                                     const float* __restrict__ Wq,
                                                     const float* __restrict__ bq,
                                                     const float* __restrict__ qnw,
                                                     const float* __restrict__ bb,
                                                     const float* __restrict__ kbase,
                                                     const unsigned short* __restrict__ kn_ws,
                                                     float* __restrict__ out)
{
    __shared__ alignas(16) char smem[36864 + 33792 + 8448];
    __shared__ float rms_l[128];
    __shared__ float l_l[128];
    __shared__ float wsm[128];
    unsigned short (*As)[72]  = (unsigned short(*)[72])smem;
    unsigned short (*Bs)[72]  = (unsigned short(*)[72])(smem + 18432);
    unsigned short (*qs)[132] = (unsigned short(*)[132])smem;           // aliases staging after GEMM
    unsigned short (*kl)[132] = (unsigned short(*)[132])(smem + 36864); // k_norm tile
    float (*kbl)[132]         = (float(*)[132])(smem + 36864 + 33792);  // k_base * q_norm_w

    const int tid  = threadIdx.x;
    const int lane = tid & 63;
    const int wv   = tid >> 6;
    const int wm   = wv >> 1, wn = wv & 1;
    const int m0   = blockIdx.x * 128;
    const int chunk = blockIdx.y;       // 0..31 = h*4+g
    const int h = chunk >> 2, g = chunk & 3;

    if (tid < 128) wsm[tid] = qnw[tid];

    const float* Ab = hid + (size_t)m0 * DIN;
    const float* Bb = Wq + (size_t)chunk * DH * DIN;

    f32x4 acc[4][4];
#pragma unroll
    for (int m = 0; m < 4; ++m)
#pragma unroll
        for (int n = 0; n < 4; ++n)
            acc[m][n] = f32x4{0.f, 0.f, 0.f, 0.f};

    const int r0 = tid >> 3;
    const int c0 = (tid & 7) * 8;
    for (int kt = 0; kt < DIN; kt += BK) {
        __syncthreads();
#pragma unroll
        for (int rr = 0; rr < 4; ++rr) {
            const int r = r0 + rr * 32;
            const float* p = Ab + (size_t)r * DIN + kt + c0;
            float4 x = *(const float4*)p;
            float4 y = *(const float4*)(p + 4);
            u32x4 v; v.x = pack2(x.x, x.y); v.y = pack2(x.z, x.w);
            v.z = pack2(y.x, y.y); v.w = pack2(y.z, y.w);
            *(u32x4*)&As[r][c0] = v;
            p = Bb + (size_t)r * DIN + kt + c0;
            x = *(const float4*)p;
            y = *(const float4*)(p + 4);
            v.x = pack2(x.x, x.y); v.y = pack2(x.z, x.w);
            v.z = pack2(y.x, y.y); v.w = pack2(y.z, y.w);
            *(u32x4*)&Bs[r][c0] = v;
        }
        __syncthreads();
#pragma unroll
        for (int kk = 0; kk < 2; ++kk) {
            s16x8 af[4], bfr[4];
#pragma unroll
            for (int m = 0; m < 4; ++m)
                af[m] = *(const s16x8*)&As[wm * 64 + m * 16 + (lane & 15)][kk * 32 + (lane >> 4) * 8];
#pragma unroll
            for (int n = 0; n < 4; ++n)
                bfr[n] = *(const s16x8*)&Bs[wn * 64 + n * 16 + (lane & 15)][kk * 32 + (lane >> 4) * 8];
#pragma unroll
            for (int m = 0; m < 4; ++m)
#pragma unroll
                for (int n = 0; n < 4; ++n)
                    acc[m][n] = __builtin_amdgcn_mfma_f32_16x16x32_bf16(af[m], bfr[n], acc[m][n], 0, 0, 0);
        }
    }
    __syncthreads();
    // acc + bq -> qs bf16 (q_raw with bias, pre-norm)
    float bqv[4];
#pragma unroll
    for (int n = 0; n < 4; ++n)
        bqv[n] = bq[chunk * DH + wn * 64 + n * 16 + (lane & 15)];
#pragma unroll
    for (int m = 0; m < 4; ++m)
#pragma unroll
        for (int n = 0; n < 4; ++n)
#pragma unroll
            for (int r = 0; r < 4; ++r)
                qs[wm * 64 + m * 16 + (lane >> 4) * 4 + r][wn * 64 + n * 16 + (lane & 15)] =
                    f2bf(acc[m][n][r] + bqv[n]);

    // stage k_norm tile (raw bf16 copy) into kl
    {
        const int r = tid >> 1, ch = (tid & 1) * 64;
        const unsigned short* src = kn_ws + (size_t)(m0 + r) * (NH * DH) + h * DH + ch;
#pragma unroll
        for (int i = 0; i < 8; ++i) {
            u32x4 v = *(const u32x4*)(src + i * 8);
            u32x2 lo; lo.x = v.x; lo.y = v.y;
            u32x2 hi; hi.x = v.z; hi.y = v.w;
            *(u32x2*)&kl[r][ch + i * 8]     = lo;
            *(u32x2*)&kl[r][ch + i * 8 + 4] = hi;
        }
    }
    // stage k_base * q_norm_w (fp32) into kbl
    {
        const int ts = tid >> 4, d0 = (tid & 15) * 8;
        const float* src = kbase + ((size_t)h * NSINK + ts) * DH + d0;
        float4 x = *(const float4*)src;
        float4 y = *(const float4*)(src + 4);
        kbl[ts][d0 + 0] = x.x * wsm[d0 + 0];
        kbl[ts][d0 + 1] = x.y * wsm[d0 + 1];
        kbl[ts][d0 + 2] = x.z * wsm[d0 + 2];
        kbl[ts][d0 + 3] = x.w * wsm[d0 + 3];
        kbl[ts][d0 + 4] = y.x * wsm[d0 + 4];
        kbl[ts][d0 + 5] = y.y * wsm[d0 + 5];
        kbl[ts][d0 + 6] = y.z * wsm[d0 + 6];
        kbl[ts][d0 + 7] = y.w * wsm[d0 + 7];
    }
    const float bval = 2.0f * bb[h * NG + g];
    __syncthreads();

    // pass2: per-row rms + k.q logit
    if (tid < 128) {
        const unsigned short* qrow = qs[tid];
        const unsigned short* krow = kl[tid];
        float s2 = 0.f, skq = 0.f;
#pragma unroll 4
        for (int dw = 0; dw < 64; ++dw) {
            unsigned int qv = *(const unsigned int*)&qrow[dw * 2];
            unsigned int kv = *(const unsigned int*)&krow[dw * 2];
            float q0 = bf2f((unsigned short)(qv & 0xffff));
            float q1 = bf2f((unsigned short)(qv >> 16));
            float k0 = bf2f((unsigned short)(kv & 0xffff));
            float k1 = bf2f((unsigned short)(kv >> 16));
            s2  += q0 * q0 + q1 * q1;
            skq += q0 * k0 * wsm[dw * 2] + q1 * k1 * wsm[dw * 2 + 1];
        }
        const float rs = rsqrtf(s2 * (1.0f / 128.0f) + 1e-6f) * 0.08838834764831845f; // rsqrt * inv_sqrt(D)
        rms_l[tid] = rs;
        l_l[tid]   = skq * rs + bval;
    }
    __syncthreads();

    // pass3: 16 sink-threads per row; sink dots + gate
    const int rloc = tid >> 4, ts = tid & 15;
    for (int pass = 0; pass < 8; ++pass) {
        const int r = pass * 16 + rloc;
        const unsigned short* qrow = qs[r];
        const float* krow = kbl[ts];
        float lb = 0.f;
#pragma unroll 4
        for (int dw = 0; dw < 64; ++dw) {
            unsigned int qv = *(const unsigned int*)&qrow[dw * 2];
            float2 kv = *(const float2*)&krow[dw * 2];
            lb += bf2f((unsigned short)(qv & 0xffff)) * kv.x +
                  bf2f((unsigned short)(qv >> 16)) * kv.y;
        }
        float e = __expf(lb * rms_l[r] - l_l[r]);
        e += __shfl_xor(e, 1);
        e += __shfl_xor(e, 2);
        e += __shfl_xor(e, 4);
        e += __shfl_xor(e, 8);
        if (ts == 0)
            atomicAdd(&out[(size_t)h * S_TOK + m0 + r], 0.25f / (1.0f + e));
    }
}

extern "C" void kernel_launch(void* const* d_in, const int* in_sizes, int n_in,
                              void* d_out, int out_size, void* d_ws, size_t ws_size,
                              hipStream_t stream)
{
    const float* hid = (const float*)d_in[0];
    const float* Wq  = (const float*)d_in[1];
    const float* bq  = (const float*)d_in[2];
    const float* Wk  = (const float*)d_in[3];
    const float* qnw = (const float*)d_in[4];
    const float* knw = (const float*)d_in[5];
    const float* bb  = (const float*)d_in[6];
    const float* kb  = (const float*)d_in[7];
    float* out = (float*)d_out;
    unsigned short* kn_ws = (unsigned short*)d_ws;  // 32768*1024 bf16 = 64 MB

    hipMemsetAsync(d_out, 0, (size_t)out_size * sizeof(float), stream);
    kproj_kernel<<<dim3(S_TOK / 128, NH), dim3(256), 0, stream>>>(hid, Wk, knw, kn_ws);
    qscore_kernel<<<dim3(S_TOK / 128, NH * NG), dim3(256), 0, stream>>>(hid, Wq, bq, qnw, bb, kb, kn_ws, out);
}

// Round 2
// 1390.150 us; speedup vs baseline: 1.3777x; 1.3777x over previous
//
#include <hip/hip_runtime.h>

#define S_TOK 32768
#define DIN   2048
#define NH    8
#define NG    4
#define DH    128
#define NSINK 16
#define BK    64

typedef float        f32x4 __attribute__((ext_vector_type(4)));
typedef short        s16x8 __attribute__((ext_vector_type(8)));
typedef unsigned int u32x4 __attribute__((ext_vector_type(4)));
typedef unsigned int u32x2 __attribute__((ext_vector_type(2)));

__device__ __forceinline__ unsigned short f2bf(float f) {
    unsigned int u = __builtin_bit_cast(unsigned int, f);
    u = (u + 0x7fffu + ((u >> 16) & 1u)) >> 16;
    return (unsigned short)u;
}
__device__ __forceinline__ float bf2f(unsigned short h) {
    unsigned int u = ((unsigned int)h) << 16;
    return __builtin_bit_cast(float, u);
}
__device__ __forceinline__ unsigned int pack2(float lo, float hi) {
    return (unsigned int)f2bf(lo) | ((unsigned int)f2bf(hi) << 16);
}

// ---------------- fp32 -> bf16 pre-conversion (grid-stride, vectorized)
__global__ __launch_bounds__(256) void cvt_bf16_kernel(const float* __restrict__ in,
                                                       unsigned short* __restrict__ out,
                                                       int n8)
{
    int i = blockIdx.x * 256 + threadIdx.x;
    const int stride = gridDim.x * 256;
    for (; i < n8; i += stride) {
        const float* p = in + (size_t)i * 8;
        float4 a = *(const float4*)p;
        float4 b = *(const float4*)(p + 4);
        u32x4 v;
        v.x = pack2(a.x, a.y); v.y = pack2(a.z, a.w);
        v.z = pack2(b.x, b.y); v.w = pack2(b.z, b.w);
        *(u32x4*)(out + (size_t)i * 8) = v;
    }
}

// ---------------- Kernel A (bf16 path): k = RMSNorm(hid @ Wk^T)*k_norm_w -> kn_ws bf16 [S][1024]
__global__ __launch_bounds__(256) void kproj_bf16(const unsigned short* __restrict__ hid,
                                                  const unsigned short* __restrict__ Wk,
                                                  const float* __restrict__ knw,
                                                  unsigned short* __restrict__ kn_ws)
{
    __shared__ alignas(16) char smem[33792];
    __shared__ float rms_l[128];
    __shared__ float wsm[128];
    unsigned short* As = (unsigned short*)smem;            // [128][64] linear
    unsigned short* Bs = (unsigned short*)(smem + 16384);  // [128][64] linear
    unsigned short (*qs)[132] = (unsigned short(*)[132])smem;  // epilogue alias

    const int tid = threadIdx.x, lane = tid & 63, wv = tid >> 6;
    const int wm = wv >> 1, wn = wv & 1;
    const int m0 = blockIdx.x * 128, h = blockIdx.y;
    if (tid < 128) wsm[tid] = knw[tid];

    const unsigned short* Ab = hid + (size_t)m0 * DIN;
    const unsigned short* Bb = Wk + (size_t)h * DH * DIN;

    f32x4 acc[4][4];
#pragma unroll
    for (int m = 0; m < 4; ++m)
#pragma unroll
        for (int n = 0; n < 4; ++n)
            acc[m][n] = f32x4{0.f, 0.f, 0.f, 0.f};

    const int lr = lane >> 3;          // row within 8-row group
    const int lc = (lane & 7) * 8;     // col element
    for (int kt = 0; kt < DIN; kt += BK) {
        __syncthreads();
#pragma unroll
        for (int i = 0; i < 4; ++i) {
            const int row = wv * 32 + i * 8;
            __builtin_amdgcn_global_load_lds(
                (const __attribute__((address_space(1))) unsigned int*)(Ab + (size_t)(row + lr) * DIN + kt + lc),
                (__attribute__((address_space(3))) unsigned int*)(As + row * BK), 16, 0, 0);
            __builtin_amdgcn_global_load_lds(
                (const __attribute__((address_space(1))) unsigned int*)(Bb + (size_t)(row + lr) * DIN + kt + lc),
                (__attribute__((address_space(3))) unsigned int*)(Bs + row * BK), 16, 0, 0);
        }
        __syncthreads();
#pragma unroll
        for (int kk = 0; kk < 2; ++kk) {
            s16x8 af[4], bfr[4];
#pragma unroll
            for (int m = 0; m < 4; ++m)
                af[m] = *(const s16x8*)&As[(wm * 64 + m * 16 + (lane & 15)) * BK + kk * 32 + (lane >> 4) * 8];
#pragma unroll
            for (int n = 0; n < 4; ++n)
                bfr[n] = *(const s16x8*)&Bs[(wn * 64 + n * 16 + (lane & 15)) * BK + kk * 32 + (lane >> 4) * 8];
#pragma unroll
            for (int m = 0; m < 4; ++m)
#pragma unroll
                for (int n = 0; n < 4; ++n)
                    acc[m][n] = __builtin_amdgcn_mfma_f32_16x16x32_bf16(af[m], bfr[n], acc[m][n], 0, 0, 0);
        }
    }
    __syncthreads();
    // acc -> qs (k_raw bf16). C layout: col = lane&15, row = (lane>>4)*4 + reg.
#pragma unroll
    for (int m = 0; m < 4; ++m)
#pragma unroll
        for (int n = 0; n < 4; ++n)
#pragma unroll
            for (int r = 0; r < 4; ++r)
                qs[wm * 64 + m * 16 + (lane >> 4) * 4 + r][wn * 64 + n * 16 + (lane & 15)] = f2bf(acc[m][n][r]);
    __syncthreads();
    if (tid < 128) {
        const unsigned short* row = qs[tid];
        float s2 = 0.f;
#pragma unroll 4
        for (int dw = 0; dw < 64; ++dw) {
            unsigned int v = *(const unsigned int*)&row[dw * 2];
            float f0 = bf2f((unsigned short)(v & 0xffff));
            float f1 = bf2f((unsigned short)(v >> 16));
            s2 += f0 * f0 + f1 * f1;
        }
        rms_l[tid] = rsqrtf(s2 * (1.0f / 128.0f) + 1e-6f);
    }
    __syncthreads();
    const int rloc = tid >> 4, cb = (tid & 15) * 8;
#pragma unroll
    for (int pass = 0; pass < 8; ++pass) {
        const int r = pass * 16 + rloc;
        const float rq = rms_l[r];
        u32x4 v;
        float f0, f1;
        f0 = bf2f(qs[r][cb + 0]) * rq * wsm[cb + 0];
        f1 = bf2f(qs[r][cb + 1]) * rq * wsm[cb + 1];
        v.x = pack2(f0, f1);
        f0 = bf2f(qs[r][cb + 2]) * rq * wsm[cb + 2];
        f1 = bf2f(qs[r][cb + 3]) * rq * wsm[cb + 3];
        v.y = pack2(f0, f1);
        f0 = bf2f(qs[r][cb + 4]) * rq * wsm[cb + 4];
        f1 = bf2f(qs[r][cb + 5]) * rq * wsm[cb + 5];
        v.z = pack2(f0, f1);
        f0 = bf2f(qs[r][cb + 6]) * rq * wsm[cb + 6];
        f1 = bf2f(qs[r][cb + 7]) * rq * wsm[cb + 7];
        v.w = pack2(f0, f1);
        *(u32x4*)&kn_ws[(size_t)(m0 + r) * (NH * DH) + h * DH + cb] = v;
    }
}

// ---------------- Kernel B (bf16 path): q-proj + RMSNorm + sink gate -> atomicAdd out
__global__ __launch_bounds__(256) void qscore_bf16(const unsigned short* __restrict__ hid,
                                                   const unsigned short* __restrict__ Wq,
                                                   const float* __restrict__ bq,
                                                   const float* __restrict__ qnw,
                                                   const float* __restrict__ bb,
                                                   const float* __restrict__ kbase,
                                                   const unsigned short* __restrict__ kn_ws,
                                                   float* __restrict__ out)
{
    __shared__ alignas(16) char smem[33792 + 33792 + 8448];
    __shared__ float rms_l[128];
    __shared__ float l_l[128];
    __shared__ float wsm[128];
    unsigned short* As = (unsigned short*)smem;            // [128][64] linear
    unsigned short* Bs = (unsigned short*)(smem + 16384);  // [128][64] linear
    unsigned short (*qs)[132] = (unsigned short(*)[132])smem;            // epilogue alias
    unsigned short (*kl)[132] = (unsigned short(*)[132])(smem + 33792);  // k_norm tile
    float (*kbl)[132]         = (float(*)[132])(smem + 33792 + 33792);   // k_base * q_norm_w

    const int tid = threadIdx.x, lane = tid & 63, wv = tid >> 6;
    const int wm = wv >> 1, wn = wv & 1;
    const int m0 = blockIdx.x * 128;
    const int chunk = blockIdx.y;         // h*4+g
    const int h = chunk >> 2, g = chunk & 3;
    if (tid < 128) wsm[tid] = qnw[tid];

    const unsigned short* Ab = hid + (size_t)m0 * DIN;
    const unsigned short* Bb = Wq + (size_t)chunk * DH * DIN;

    f32x4 acc[4][4];
#pragma unroll
    for (int m = 0; m < 4; ++m)
#pragma unroll
        for (int n = 0; n < 4; ++n)
            acc[m][n] = f32x4{0.f, 0.f, 0.f, 0.f};

    const int lr = lane >> 3;
    const int lc = (lane & 7) * 8;
    for (int kt = 0; kt < DIN; kt += BK) {
        __syncthreads();
#pragma unroll
        for (int i = 0; i < 4; ++i) {
            const int row = wv * 32 + i * 8;
            __builtin_amdgcn_global_load_lds(
                (const __attribute__((address_space(1))) unsigned int*)(Ab + (size_t)(row + lr) * DIN + kt + lc),
                (__attribute__((address_space(3))) unsigned int*)(As + row * BK), 16, 0, 0);
            __builtin_amdgcn_global_load_lds(
                (const __attribute__((address_space(1))) unsigned int*)(Bb + (size_t)(row + lr) * DIN + kt + lc),
                (__attribute__((address_space(3))) unsigned int*)(Bs + row * BK), 16, 0, 0);
        }
        __syncthreads();
#pragma unroll
        for (int kk = 0; kk < 2; ++kk) {
            s16x8 af[4], bfr[4];
#pragma unroll
            for (int m = 0; m < 4; ++m)
                af[m] = *(const s16x8*)&As[(wm * 64 + m * 16 + (lane & 15)) * BK + kk * 32 + (lane >> 4) * 8];
#pragma unroll
            for (int n = 0; n < 4; ++n)
                bfr[n] = *(const s16x8*)&Bs[(wn * 64 + n * 16 + (lane & 15)) * BK + kk * 32 + (lane >> 4) * 8];
#pragma unroll
            for (int m = 0; m < 4; ++m)
#pragma unroll
                for (int n = 0; n < 4; ++n)
                    acc[m][n] = __builtin_amdgcn_mfma_f32_16x16x32_bf16(af[m], bfr[n], acc[m][n], 0, 0, 0);
        }
    }
    __syncthreads();
    // acc + bq -> qs bf16 (q_raw with bias, pre-norm)
    float bqv[4];
#pragma unroll
    for (int n = 0; n < 4; ++n)
        bqv[n] = bq[chunk * DH + wn * 64 + n * 16 + (lane & 15)];
#pragma unroll
    for (int m = 0; m < 4; ++m)
#pragma unroll
        for (int n = 0; n < 4; ++n)
#pragma unroll
            for (int r = 0; r < 4; ++r)
                qs[wm * 64 + m * 16 + (lane >> 4) * 4 + r][wn * 64 + n * 16 + (lane & 15)] =
                    f2bf(acc[m][n][r] + bqv[n]);

    // stage k_norm tile
    {
        const int r = tid >> 1, ch = (tid & 1) * 64;
        const unsigned short* src = kn_ws + (size_t)(m0 + r) * (NH * DH) + h * DH + ch;
#pragma unroll
        for (int i = 0; i < 8; ++i) {
            u32x4 v = *(const u32x4*)(src + i * 8);
            u32x2 lo; lo.x = v.x; lo.y = v.y;
            u32x2 hi; hi.x = v.z; hi.y = v.w;
            *(u32x2*)&kl[r][ch + i * 8]     = lo;
            *(u32x2*)&kl[r][ch + i * 8 + 4] = hi;
        }
    }
    // stage k_base * q_norm_w (fp32)
    {
        const int ts = tid >> 4, d0 = (tid & 15) * 8;
        const float* src = kbase + ((size_t)h * NSINK + ts) * DH + d0;
        float4 x = *(const float4*)src;
        float4 y = *(const float4*)(src + 4);
        kbl[ts][d0 + 0] = x.x * wsm[d0 + 0];
        kbl[ts][d0 + 1] = x.y * wsm[d0 + 1];
        kbl[ts][d0 + 2] = x.z * wsm[d0 + 2];
        kbl[ts][d0 + 3] = x.w * wsm[d0 + 3];
        kbl[ts][d0 + 4] = y.x * wsm[d0 + 4];
        kbl[ts][d0 + 5] = y.y * wsm[d0 + 5];
        kbl[ts][d0 + 6] = y.z * wsm[d0 + 6];
        kbl[ts][d0 + 7] = y.w * wsm[d0 + 7];
    }
    const float bval = 2.0f * bb[h * NG + g];
    __syncthreads();

    // pass2: per-row rms + k.q logit
    if (tid < 128) {
        const unsigned short* qrow = qs[tid];
        const unsigned short* krow = kl[tid];
        float s2 = 0.f, skq = 0.f;
#pragma unroll 4
        for (int dw = 0; dw < 64; ++dw) {
            unsigned int qv = *(const unsigned int*)&qrow[dw * 2];
            unsigned int kv = *(const unsigned int*)&krow[dw * 2];
            float q0 = bf2f((unsigned short)(qv & 0xffff));
            float q1 = bf2f((unsigned short)(qv >> 16));
            float k0 = bf2f((unsigned short)(kv & 0xffff));
            float k1 = bf2f((unsigned short)(kv >> 16));
            s2  += q0 * q0 + q1 * q1;
            skq += q0 * k0 * wsm[dw * 2] + q1 * k1 * wsm[dw * 2 + 1];
        }
        const float rs = rsqrtf(s2 * (1.0f / 128.0f) + 1e-6f) * 0.08838834764831845f;
        rms_l[tid] = rs;
        l_l[tid]   = skq * rs + bval;
    }
    __syncthreads();

    // pass3: sink dots + gate
    const int rloc = tid >> 4, ts = tid & 15;
    for (int pass = 0; pass < 8; ++pass) {
        const int r = pass * 16 + rloc;
        const unsigned short* qrow = qs[r];
        const float* krow = kbl[ts];
        float lb = 0.f;
#pragma unroll 4
        for (int dw = 0; dw < 64; ++dw) {
            unsigned int qv = *(const unsigned int*)&qrow[dw * 2];
            float2 kv = *(const float2*)&krow[dw * 2];
            lb += bf2f((unsigned short)(qv & 0xffff)) * kv.x +
                  bf2f((unsigned short)(qv >> 16)) * kv.y;
        }
        float e = __expf(lb * rms_l[r] - l_l[r]);
        e += __shfl_xor(e, 1);
        e += __shfl_xor(e, 2);
        e += __shfl_xor(e, 4);
        e += __shfl_xor(e, 8);
        if (ts == 0)
            atomicAdd(&out[(size_t)h * S_TOK + m0 + r], 0.25f / (1.0f + e));
    }
}

// ================= Fallback path (R1 kernels, fp32 reg-staged) — used if ws too small =================
__global__ __launch_bounds__(256) void kproj_kernel(const float* __restrict__ hid,
                                                    const float* __restrict__ Wk,
                                                    const float* __restrict__ knw,
                                                    unsigned short* __restrict__ kn_ws)
{
    __shared__ alignas(16) char smem[36864];
    __shared__ float rms_l[128];
    __shared__ float wsm[128];
    unsigned short (*As)[72]  = (unsigned short(*)[72])smem;
    unsigned short (*Bs)[72]  = (unsigned short(*)[72])(smem + 18432);
    unsigned short (*qs)[132] = (unsigned short(*)[132])smem;

    const int tid  = threadIdx.x;
    const int lane = tid & 63;
    const int wv   = tid >> 6;
    const int wm   = wv >> 1, wn = wv & 1;
    const int m0   = blockIdx.x * 128;
    const int h    = blockIdx.y;

    if (tid < 128) wsm[tid] = knw[tid];

    const float* Ab = hid + (size_t)m0 * DIN;
    const float* Bb = Wk + (size_t)h * DH * DIN;

    f32x4 acc[4][4];
#pragma unroll
    for (int m = 0; m < 4; ++m)
#pragma unroll
        for (int n = 0; n < 4; ++n)
            acc[m][n] = f32x4{0.f, 0.f, 0.f, 0.f};

    const int r0 = tid >> 3;
    const int c0 = (tid & 7) * 8;
    for (int kt = 0; kt < DIN; kt += BK) {
        __syncthreads();
#pragma unroll
        for (int rr = 0; rr < 4; ++rr) {
            const int r = r0 + rr * 32;
            const float* p = Ab + (size_t)r * DIN + kt + c0;
            float4 x = *(const float4*)p;
            float4 y = *(const float4*)(p + 4);
            u32x4 v; v.x = pack2(x.x, x.y); v.y = pack2(x.z, x.w);
            v.z = pack2(y.x, y.y); v.w = pack2(y.z, y.w);
            *(u32x4*)&As[r][c0] = v;
            p = Bb + (size_t)r * DIN + kt + c0;
            x = *(const float4*)p;
            y = *(const float4*)(p + 4);
            v.x = pack2(x.x, x.y); v.y = pack2(x.z, x.w);
            v.z = pack2(y.x, y.y); v.w = pack2(y.z, y.w);
            *(u32x4*)&Bs[r][c0] = v;
        }
        __syncthreads();
#pragma unroll
        for (int kk = 0; kk < 2; ++kk) {
            s16x8 af[4], bfr[4];
#pragma unroll
            for (int m = 0; m < 4; ++m)
                af[m] = *(const s16x8*)&As[wm * 64 + m * 16 + (lane & 15)][kk * 32 + (lane >> 4) * 8];
#pragma unroll
            for (int n = 0; n < 4; ++n)
                bfr[n] = *(const s16x8*)&Bs[wn * 64 + n * 16 + (lane & 15)][kk * 32 + (lane >> 4) * 8];
#pragma unroll
            for (int m = 0; m < 4; ++m)
#pragma unroll
                for (int n = 0; n < 4; ++n)
                    acc[m][n] = __builtin_amdgcn_mfma_f32_16x16x32_bf16(af[m], bfr[n], acc[m][n], 0, 0, 0);
        }
    }
    __syncthreads();
#pragma unroll
    for (int m = 0; m < 4; ++m)
#pragma unroll
        for (int n = 0; n < 4; ++n)
#pragma unroll
            for (int r = 0; r < 4; ++r)
                qs[wm * 64 + m * 16 + (lane >> 4) * 4 + r][wn * 64 + n * 16 + (lane & 15)] = f2bf(acc[m][n][r]);
    __syncthreads();
    if (tid < 128) {
        const unsigned short* row = qs[tid];
        float s2 = 0.f;
#pragma unroll 4
        for (int dw = 0; dw < 64; ++dw) {
            unsigned int v = *(const unsigned int*)&row[dw * 2];
            float f0 = bf2f((unsigned short)(v & 0xffff));
            float f1 = bf2f((unsigned short)(v >> 16));
            s2 += f0 * f0 + f1 * f1;
        }
        rms_l[tid] = rsqrtf(s2 * (1.0f / 128.0f) + 1e-6f);
    }
    __syncthreads();
    const int rloc = tid >> 4, cb = (tid & 15) * 8;
#pragma unroll
    for (int pass = 0; pass < 8; ++pass) {
        const int r = pass * 16 + rloc;
        const float rq = rms_l[r];
        u32x4 v;
        float f0, f1;
        f0 = bf2f(qs[r][cb + 0]) * rq * wsm[cb + 0];
        f1 = bf2f(qs[r][cb + 1]) * rq * wsm[cb + 1];
        v.x = pack2(f0, f1);
        f0 = bf2f(qs[r][cb + 2]) * rq * wsm[cb + 2];
        f1 = bf2f(qs[r][cb + 3]) * rq * wsm[cb + 3];
        v.y = pack2(f0, f1);
        f0 = bf2f(qs[r][cb + 4]) * rq * wsm[cb + 4];
        f1 = bf2f(qs[r][cb + 5]) * rq * wsm[cb + 5];
        v.z = pack2(f0, f1);
        f0 = bf2f(qs[r][cb + 6]) * rq * wsm[cb + 6];
        f1 = bf2f(qs[r][cb + 7]) * rq * wsm[cb + 7];
        v.w = pack2(f0, f1);
        *(u32x4*)&kn_ws[(size_t)(m0 + r) * (NH * DH) + h * DH + cb] = v;
    }
}

__global__ __launch_bounds__(256) void qscore_kernel(const float* __restrict__ hid,
                                                     const float* __restrict__ Wq,
                                                     const float* __restrict__ bq,
                                                     const float* __restrict__ qnw,
                                                     const float* __restrict__ bb,
                                                     const float* __restrict__ kbase,
                                                     const unsigned short* __restrict__ kn_ws,
                                                     float* __restrict__ out)
{
    __shared__ alignas(16) char smem[36864 + 33792 + 8448];
    __shared__ float rms_l[128];
    __shared__ float l_l[128];
    __shared__ float wsm[128];
    unsigned short (*As)[72]  = (unsigned short(*)[72])smem;
    unsigned short (*Bs)[72]  = (unsigned short(*)[72])(smem + 18432);
    unsigned short (*qs)[132] = (unsigned short(*)[132])smem;
    unsigned short (*kl)[132] = (unsigned short(*)[132])(smem + 36864);
    float (*kbl)[132]         = (float(*)[132])(smem + 36864 + 33792);

    const int tid  = threadIdx.x;
    const int lane = tid & 63;
    const int wv   = tid >> 6;
    const int wm   = wv >> 1, wn = wv & 1;
    const int m0   = blockIdx.x * 128;
    const int chunk = blockIdx.y;
    const int h = chunk >> 2, g = chunk & 3;

    if (tid < 128) wsm[tid] = qnw[tid];

    const float* Ab = hid + (size_t)m0 * DIN;
    const float* Bb = Wq + (size_t)chunk * DH * DIN;

    f32x4 acc[4][4];
#pragma unroll
    for (int m = 0; m < 4; ++m)
#pragma unroll
        for (int n = 0; n < 4; ++n)
            acc[m][n] = f32x4{0.f, 0.f, 0.f, 0.f};

    const int r0 = tid >> 3;
    const int c0 = (tid & 7) * 8;
    for (int kt = 0; kt < DIN; kt += BK) {
        __syncthreads();
#pragma unroll
        for (int rr = 0; rr < 4; ++rr) {
            const int r = r0 + rr * 32;
            const float* p = Ab + (size_t)r * DIN + kt + c0;
            float4 x = *(const float4*)p;
            float4 y = *(const float4*)(p + 4);
            u32x4 v; v.x = pack2(x.x, x.y); v.y = pack2(x.z, x.w);
            v.z = pack2(y.x, y.y); v.w = pack2(y.z, y.w);
            *(u32x4*)&As[r][c0] = v;
            p = Bb + (size_t)r * DIN + kt + c0;
            x = *(const float4*)p;
            y = *(const float4*)(p + 4);
            v.x = pack2(x.x, x.y); v.y = pack2(x.z, x.w);
            v.z = pack2(y.x, y.y); v.w = pack2(y.z, y.w);
            *(u32x4*)&Bs[r][c0] = v;
        }
        __syncthreads();
#pragma unroll
        for (int kk = 0; kk < 2; ++kk) {
            s16x8 af[4], bfr[4];
#pragma unroll
            for (int m = 0; m < 4; ++m)
                af[m] = *(const s16x8*)&As[wm * 64 + m * 16 + (lane & 15)][kk * 32 + (lane >> 4) * 8];
#pragma unroll
            for (int n = 0; n < 4; ++n)
                bfr[n] = *(const s16x8*)&Bs[wn * 64 + n * 16 + (lane & 15)][kk * 32 + (lane >> 4) * 8];
#pragma unroll
            for (int m = 0; m < 4; ++m)
#pragma unroll
                for (int n = 0; n < 4; ++n)
                    acc[m][n] = __builtin_amdgcn_mfma_f32_16x16x32_bf16(af[m], bfr[n], acc[m][n], 0, 0, 0);
        }
    }
    __syncthreads();
    float bqv[4];
#pragma unroll
    for (int n = 0; n < 4; ++n)
        bqv[n] = bq[chunk * DH + wn * 64 + n * 16 + (lane & 15)];
#pragma unroll
    for (int m = 0; m < 4; ++m)
#pragma unroll
        for (int n = 0; n < 4; ++n)
#pragma unroll
            for (int r = 0; r < 4; ++r)
                qs[wm * 64 + m * 16 + (lane >> 4) * 4 + r][wn * 64 + n * 16 + (lane & 15)] =
                    f2bf(acc[m][n][r] + bqv[n]);

    {
        const int r = tid >> 1, ch = (tid & 1) * 64;
        const unsigned short* src = kn_ws + (size_t)(m0 + r) * (NH * DH) + h * DH + ch;
#pragma unroll
        for (int i = 0; i < 8; ++i) {
            u32x4 v = *(const u32x4*)(src + i * 8);
            u32x2 lo; lo.x = v.x; lo.y = v.y;
            u32x2 hi; hi.x = v.z; hi.y = v.w;
            *(u32x2*)&kl[r][ch + i * 8]     = lo;
            *(u32x2*)&kl[r][ch + i * 8 + 4] = hi;
        }
    }
    {
        const int ts = tid >> 4, d0 = (tid & 15) * 8;
        const float* src = kbase + ((size_t)h * NSINK + ts) * DH + d0;
        float4 x = *(const float4*)src;
        float4 y = *(const float4*)(src + 4);
        kbl[ts][d0 + 0] = x.x * wsm[d0 + 0];
        kbl[ts][d0 + 1] = x.y * wsm[d0 + 1];
        kbl[ts][d0 + 2] = x.z * wsm[d0 + 2];
        kbl[ts][d0 + 3] = x.w * wsm[d0 + 3];
        kbl[ts][d0 + 4] = y.x * wsm[d0 + 4];
        kbl[ts][d0 + 5] = y.y * wsm[d0 + 5];
        kbl[ts][d0 + 6] = y.z * wsm[d0 + 6];
        kbl[ts][d0 + 7] = y.w * wsm[d0 + 7];
    }
    const float bval = 2.0f * bb[h * NG + g];
    __syncthreads();

    if (tid < 128) {
        const unsigned short* qrow = qs[tid];
        const unsigned short* krow = kl[tid];
        float s2 = 0.f, skq = 0.f;
#pragma unroll 4
        for (int dw = 0; dw < 64; ++dw) {
            unsigned int qv = *(const unsigned int*)&qrow[dw * 2];
            unsigned int kv = *(const unsigned int*)&krow[dw * 2];
            float q0 = bf2f((unsigned short)(qv & 0xffff));
            float q1 = bf2f((unsigned short)(qv >> 16));
            float k0 = bf2f((unsigned short)(kv & 0xffff));
            float k1 = bf2f((unsigned short)(kv >> 16));
            s2  += q0 * q0 + q1 * q1;
            skq += q0 * k0 * wsm[dw * 2] + q1 * k1 * wsm[dw * 2 + 1];
        }
        const float rs = rsqrtf(s2 * (1.0f / 128.0f) + 1e-6f) * 0.08838834764831845f;
        rms_l[tid] = rs;
        l_l[tid]   = skq * rs + bval;
    }
    __syncthreads();

    const int rloc = tid >> 4, ts = tid & 15;
    for (int pass = 0; pass < 8; ++pass) {
        const int r = pass * 16 + rloc;
        const unsigned short* qrow = qs[r];
        const float* krow = kbl[ts];
        float lb = 0.f;
#pragma unroll 4
        for (int dw = 0; dw < 64; ++dw) {
            unsigned int qv = *(const unsigned int*)&qrow[dw * 2];
            float2 kv = *(const float2*)&krow[dw * 2];
            lb += bf2f((unsigned short)(qv & 0xffff)) * kv.x +
                  bf2f((unsigned short)(qv >> 16)) * kv.y;
        }
        float e = __expf(lb * rms_l[r] - l_l[r]);
        e += __shfl_xor(e, 1);
        e += __shfl_xor(e, 2);
        e += __shfl_xor(e, 4);
        e += __shfl_xor(e, 8);
        if (ts == 0)
            atomicAdd(&out[(size_t)h * S_TOK + m0 + r], 0.25f / (1.0f + e));
    }
}

extern "C" void kernel_launch(void* const* d_in, const int* in_sizes, int n_in,
                              void* d_out, int out_size, void* d_ws, size_t ws_size,
                              hipStream_t stream)
{
    const float* hid = (const float*)d_in[0];
    const float* Wq  = (const float*)d_in[1];
    const float* bq  = (const float*)d_in[2];
    const float* Wk  = (const float*)d_in[3];
    const float* qnw = (const float*)d_in[4];
    const float* knw = (const float*)d_in[5];
    const float* bb  = (const float*)d_in[6];
    const float* kb  = (const float*)d_in[7];
    float* out = (float*)d_out;

    hipMemsetAsync(d_out, 0, (size_t)out_size * sizeof(float), stream);

    const size_t HID_E = (size_t)S_TOK * DIN;          // 67.1M
    const size_t WQ_E  = (size_t)NH * NG * DH * DIN;   // 8.4M
    const size_t WK_E  = (size_t)NH * DH * DIN;        // 2.1M
    const size_t KN_B  = (size_t)S_TOK * NH * DH * 2;  // 64 MB
    const size_t need  = (HID_E + WQ_E + WK_E) * 2 + KN_B;

    if (ws_size >= need) {
        unsigned short* hid_b = (unsigned short*)d_ws;
        unsigned short* wq_b  = hid_b + HID_E;
        unsigned short* wk_b  = wq_b + WQ_E;
        unsigned short* kn_ws = wk_b + WK_E;

        cvt_bf16_kernel<<<2048, 256, 0, stream>>>(hid, hid_b, (int)(HID_E / 8));
        cvt_bf16_kernel<<<512, 256, 0, stream>>>(Wq, wq_b, (int)(WQ_E / 8));
        cvt_bf16_kernel<<<256, 256, 0, stream>>>(Wk, wk_b, (int)(WK_E / 8));

        kproj_bf16<<<dim3(S_TOK / 128, NH), dim3(256), 0, stream>>>(hid_b, wk_b, knw, kn_ws);
        qscore_bf16<<<dim3(S_TOK / 128, NH * NG), dim3(256), 0, stream>>>(hid_b, wq_b, bq, qnw, bb, kb, kn_ws, out);
    } else {
        unsigned short* kn_ws = (unsigned short*)d_ws;
        kproj_kernel<<<dim3(S_TOK / 128, NH), dim3(256), 0, stream>>>(hid, Wk, knw, kn_ws);
        qscore_kernel<<<dim3(S_TOK / 128, NH * NG), dim3(256), 0, stream>>>(hid, Wq, bq, qnw, bb, kb, kn_ws, out);
    }
}

// Round 3
// 1121.950 us; speedup vs baseline: 1.7071x; 1.2390x over previous
//
#include <hip/hip_runtime.h>

#define S_TOK 32768
#define DIN   2048
#define NH    8
#define NG    4
#define DH    128
#define NSINK 16
#define BK    64

typedef float        f32x4 __attribute__((ext_vector_type(4)));
typedef short        s16x8 __attribute__((ext_vector_type(8)));
typedef unsigned int u32x4 __attribute__((ext_vector_type(4)));
typedef unsigned int u32x2 __attribute__((ext_vector_type(2)));

__device__ __forceinline__ unsigned short f2bf(float f) {
    unsigned int u = __builtin_bit_cast(unsigned int, f);
    u = (u + 0x7fffu + ((u >> 16) & 1u)) >> 16;
    return (unsigned short)u;
}
__device__ __forceinline__ float bf2f(unsigned short h) {
    unsigned int u = ((unsigned int)h) << 16;
    return __builtin_bit_cast(float, u);
}
__device__ __forceinline__ unsigned int pack2(float lo, float hi) {
    return (unsigned int)f2bf(lo) | ((unsigned int)f2bf(hi) << 16);
}

// ---------------- fp32 -> bf16 pre-conversion (grid-stride, vectorized)
__global__ __launch_bounds__(256) void cvt_bf16_kernel(const float* __restrict__ in,
                                                       unsigned short* __restrict__ out,
                                                       int n8)
{
    int i = blockIdx.x * 256 + threadIdx.x;
    const int stride = gridDim.x * 256;
    for (; i < n8; i += stride) {
        const float* p = in + (size_t)i * 8;
        float4 a = *(const float4*)p;
        float4 b = *(const float4*)(p + 4);
        u32x4 v;
        v.x = pack2(a.x, a.y); v.y = pack2(a.z, a.w);
        v.z = pack2(b.x, b.y); v.w = pack2(b.z, b.w);
        *(u32x4*)(out + (size_t)i * 8) = v;
    }
}

// Staged LDS layout (both A and B tiles): [128 rows][8 granules of 8 bf16].
// Stored granule slot s of row r holds global granule s ^ (r&7)   (st-style XOR
// swizzle realized by pre-swizzling the per-lane GLOBAL address; LDS dest linear
// as required by global_load_lds). Read of global granule g of row r -> slot
// g ^ (r&7).

// ---------------- Kernel A: k = RMSNorm(hid @ Wk^T)*k_norm_w -> kn_ws bf16 [S][1024]
__global__ __launch_bounds__(256) void kproj_bf16(const unsigned short* __restrict__ hid,
                                                  const unsigned short* __restrict__ Wk,
                                                  const float* __restrict__ knw,
                                                  unsigned short* __restrict__ kn_ws)
{
    __shared__ alignas(16) char smem[33792];   // staging (32 KB) aliased with qs (33 KB)
    __shared__ float rms_l[128];
    __shared__ float wsm[128];
    unsigned short* As = (unsigned short*)smem;            // [128][64] swizzled
    unsigned short* Bs = (unsigned short*)(smem + 16384);  // [128][64] swizzled
    unsigned short (*qs)[132] = (unsigned short(*)[132])smem;  // epilogue alias

    const int tid = threadIdx.x, lane = tid & 63, wv = tid >> 6;
    const int wm = wv >> 1, wn = wv & 1;
    const int h = blockIdx.x, m0 = blockIdx.y * 128;
    if (tid < 128) wsm[tid] = knw[tid];

    const unsigned short* Ab = hid + (size_t)m0 * DIN;
    const unsigned short* Bb = Wk + (size_t)h * DH * DIN;

    f32x4 acc[4][4];
#pragma unroll
    for (int m = 0; m < 4; ++m)
#pragma unroll
        for (int n = 0; n < 4; ++n)
            acc[m][n] = f32x4{0.f, 0.f, 0.f, 0.f};

    const int lr = lane >> 3;                         // row within 8-row group
    const int lc = (((lane & 7) ^ lr) * 8);           // pre-swizzled global granule
    for (int kt = 0; kt < DIN; kt += BK) {
        __syncthreads();
#pragma unroll
        for (int i = 0; i < 4; ++i) {
            const int row = wv * 32 + i * 8;
            __builtin_amdgcn_global_load_lds(
                (const __attribute__((address_space(1))) unsigned int*)(Ab + (size_t)(row + lr) * DIN + kt + lc),
                (__attribute__((address_space(3))) unsigned int*)(As + row * BK), 16, 0, 0);
            __builtin_amdgcn_global_load_lds(
                (const __attribute__((address_space(1))) unsigned int*)(Bb + (size_t)(row + lr) * DIN + kt + lc),
                (__attribute__((address_space(3))) unsigned int*)(Bs + row * BK), 16, 0, 0);
        }
        __syncthreads();
#pragma unroll
        for (int kk = 0; kk < 2; ++kk) {
            s16x8 af[4], bfr[4];
            const int g0 = kk * 4 + (lane >> 4);      // global granule wanted
            const int slot = (g0 ^ (lane & 7)) * 8;   // swizzled slot ((row&7)==lane&7)
#pragma unroll
            for (int m = 0; m < 4; ++m)
                af[m] = *(const s16x8*)&As[(wm * 64 + m * 16 + (lane & 15)) * BK + slot];
#pragma unroll
            for (int n = 0; n < 4; ++n)
                bfr[n] = *(const s16x8*)&Bs[(wn * 64 + n * 16 + (lane & 15)) * BK + slot];
#pragma unroll
            for (int m = 0; m < 4; ++m)
#pragma unroll
                for (int n = 0; n < 4; ++n)
                    acc[m][n] = __builtin_amdgcn_mfma_f32_16x16x32_bf16(af[m], bfr[n], acc[m][n], 0, 0, 0);
        }
    }
    __syncthreads();
    // acc -> qs (k_raw bf16). C layout: col = lane&15, row = (lane>>4)*4 + reg.
#pragma unroll
    for (int m = 0; m < 4; ++m)
#pragma unroll
        for (int n = 0; n < 4; ++n)
#pragma unroll
            for (int r = 0; r < 4; ++r)
                qs[wm * 64 + m * 16 + (lane >> 4) * 4 + r][wn * 64 + n * 16 + (lane & 15)] = f2bf(acc[m][n][r]);
    __syncthreads();
    if (tid < 128) {
        const unsigned short* row = qs[tid];
        float s2 = 0.f;
#pragma unroll 4
        for (int dw = 0; dw < 64; ++dw) {
            unsigned int v = *(const unsigned int*)&row[dw * 2];
            float f0 = bf2f((unsigned short)(v & 0xffff));
            float f1 = bf2f((unsigned short)(v >> 16));
            s2 += f0 * f0 + f1 * f1;
        }
        rms_l[tid] = rsqrtf(s2 * (1.0f / 128.0f) + 1e-6f);
    }
    __syncthreads();
    const int rloc = tid >> 4, cb = (tid & 15) * 8;
#pragma unroll
    for (int pass = 0; pass < 8; ++pass) {
        const int r = pass * 16 + rloc;
        const float rq = rms_l[r];
        u32x4 v;
        float f0, f1;
        f0 = bf2f(qs[r][cb + 0]) * rq * wsm[cb + 0];
        f1 = bf2f(qs[r][cb + 1]) * rq * wsm[cb + 1];
        v.x = pack2(f0, f1);
        f0 = bf2f(qs[r][cb + 2]) * rq * wsm[cb + 2];
        f1 = bf2f(qs[r][cb + 3]) * rq * wsm[cb + 3];
        v.y = pack2(f0, f1);
        f0 = bf2f(qs[r][cb + 4]) * rq * wsm[cb + 4];
        f1 = bf2f(qs[r][cb + 5]) * rq * wsm[cb + 5];
        v.z = pack2(f0, f1);
        f0 = bf2f(qs[r][cb + 6]) * rq * wsm[cb + 6];
        f1 = bf2f(qs[r][cb + 7]) * rq * wsm[cb + 7];
        v.w = pack2(f0, f1);
        *(u32x4*)&kn_ws[(size_t)(m0 + r) * (NH * DH) + h * DH + cb] = v;
    }
}

// ---------------- Kernel B: q-proj + RMSNorm + sink gate -> atomicAdd out
__global__ __launch_bounds__(256) void qscore_bf16(const unsigned short* __restrict__ hid,
                                                   const unsigned short* __restrict__ Wq,
                                                   const float* __restrict__ bq,
                                                   const float* __restrict__ qnw,
                                                   const float* __restrict__ bb,
                                                   const float* __restrict__ kbase,
                                                   const unsigned short* __restrict__ kn_ws,
                                                   float* __restrict__ out)
{
    __shared__ alignas(16) char smem[33792];   // staging (32 KB) aliased with qs (33 KB)
    __shared__ alignas(16) float kbl[NSINK][132];  // k_base * q_norm_w
    __shared__ float rms_l[128];
    __shared__ float l_l[128];
    __shared__ float wsm[128];
    unsigned short* As = (unsigned short*)smem;            // [128][64] swizzled
    unsigned short* Bs = (unsigned short*)(smem + 16384);  // [128][64] swizzled
    unsigned short (*qs)[132] = (unsigned short(*)[132])smem;  // epilogue alias

    const int tid = threadIdx.x, lane = tid & 63, wv = tid >> 6;
    const int wm = wv >> 1, wn = wv & 1;
    const int chunk = blockIdx.x;         // h*4+g  (chunk-fast: A-tile shared by 32 adjacent blocks)
    const int m0 = blockIdx.y * 128;
    const int h = chunk >> 2, g = chunk & 3;
    if (tid < 128) wsm[tid] = qnw[tid];

    const unsigned short* Ab = hid + (size_t)m0 * DIN;
    const unsigned short* Bb = Wq + (size_t)chunk * DH * DIN;

    f32x4 acc[4][4];
#pragma unroll
    for (int m = 0; m < 4; ++m)
#pragma unroll
        for (int n = 0; n < 4; ++n)
            acc[m][n] = f32x4{0.f, 0.f, 0.f, 0.f};

    const int lr = lane >> 3;
    const int lc = (((lane & 7) ^ lr) * 8);
    for (int kt = 0; kt < DIN; kt += BK) {
        __syncthreads();
#pragma unroll
        for (int i = 0; i < 4; ++i) {
            const int row = wv * 32 + i * 8;
            __builtin_amdgcn_global_load_lds(
                (const __attribute__((address_space(1))) unsigned int*)(Ab + (size_t)(row + lr) * DIN + kt + lc),
                (__attribute__((address_space(3))) unsigned int*)(As + row * BK), 16, 0, 0);
            __builtin_amdgcn_global_load_lds(
                (const __attribute__((address_space(1))) unsigned int*)(Bb + (size_t)(row + lr) * DIN + kt + lc),
                (__attribute__((address_space(3))) unsigned int*)(Bs + row * BK), 16, 0, 0);
        }
        __syncthreads();
#pragma unroll
        for (int kk = 0; kk < 2; ++kk) {
            s16x8 af[4], bfr[4];
            const int g0 = kk * 4 + (lane >> 4);
            const int slot = (g0 ^ (lane & 7)) * 8;
#pragma unroll
            for (int m = 0; m < 4; ++m)
                af[m] = *(const s16x8*)&As[(wm * 64 + m * 16 + (lane & 15)) * BK + slot];
#pragma unroll
            for (int n = 0; n < 4; ++n)
                bfr[n] = *(const s16x8*)&Bs[(wn * 64 + n * 16 + (lane & 15)) * BK + slot];
#pragma unroll
            for (int m = 0; m < 4; ++m)
#pragma unroll
                for (int n = 0; n < 4; ++n)
                    acc[m][n] = __builtin_amdgcn_mfma_f32_16x16x32_bf16(af[m], bfr[n], acc[m][n], 0, 0, 0);
        }
    }

    // stage k_base * q_norm_w (fp32) into kbl (no dependence on staging buffers)
    {
        const int ts = tid >> 4, d0 = (tid & 15) * 8;
        const float* src = kbase + ((size_t)h * NSINK + ts) * DH + d0;
        float4 x = *(const float4*)src;
        float4 y = *(const float4*)(src + 4);
        kbl[ts][d0 + 0] = x.x * wsm[d0 + 0];
        kbl[ts][d0 + 1] = x.y * wsm[d0 + 1];
        kbl[ts][d0 + 2] = x.z * wsm[d0 + 2];
        kbl[ts][d0 + 3] = x.w * wsm[d0 + 3];
        kbl[ts][d0 + 4] = y.x * wsm[d0 + 4];
        kbl[ts][d0 + 5] = y.y * wsm[d0 + 5];
        kbl[ts][d0 + 6] = y.z * wsm[d0 + 6];
        kbl[ts][d0 + 7] = y.w * wsm[d0 + 7];
    }

    __syncthreads();
    // acc + bq -> qs bf16 (q_raw with bias, pre-norm)
    float bqv[4];
#pragma unroll
    for (int n = 0; n < 4; ++n)
        bqv[n] = bq[chunk * DH + wn * 64 + n * 16 + (lane & 15)];
#pragma unroll
    for (int m = 0; m < 4; ++m)
#pragma unroll
        for (int n = 0; n < 4; ++n)
#pragma unroll
            for (int r = 0; r < 4; ++r)
                qs[wm * 64 + m * 16 + (lane >> 4) * 4 + r][wn * 64 + n * 16 + (lane & 15)] =
                    f2bf(acc[m][n][r] + bqv[n]);

    const float bval = 2.0f * bb[h * NG + g];
    __syncthreads();

    // pass2: all 256 threads; pair (2 threads) per row; k_norm read straight from L2-resident ws
    {
        const int r2 = tid >> 1, ch = (tid & 1) * 64;
        const unsigned short* qrow = &qs[r2][ch];
        const unsigned short* kg = kn_ws + (size_t)(m0 + r2) * (NH * DH) + h * DH + ch;
        const float* wp = &wsm[ch];
        float s2 = 0.f, skq = 0.f;
#pragma unroll 2
        for (int i = 0; i < 8; ++i) {
            u32x4 kv = *(const u32x4*)(kg + i * 8);
#pragma unroll
            for (int j = 0; j < 4; ++j) {
                unsigned int qv = *(const unsigned int*)&qrow[i * 8 + j * 2];
                unsigned int kw = kv[j];
                float q0 = bf2f((unsigned short)(qv & 0xffff));
                float q1 = bf2f((unsigned short)(qv >> 16));
                float k0 = bf2f((unsigned short)(kw & 0xffff));
                float k1 = bf2f((unsigned short)(kw >> 16));
                s2  += q0 * q0 + q1 * q1;
                skq += q0 * k0 * wp[i * 8 + j * 2] + q1 * k1 * wp[i * 8 + j * 2 + 1];
            }
        }
        s2  += __shfl_xor(s2, 1);
        skq += __shfl_xor(skq, 1);
        if ((tid & 1) == 0) {
            const float rs = rsqrtf(s2 * (1.0f / 128.0f) + 1e-6f) * 0.08838834764831845f;
            rms_l[r2] = rs;
            l_l[r2]   = skq * rs + bval;
        }
    }
    __syncthreads();

    // pass3: 16 sink-threads per row; sink dots + gate
    const int rloc = tid >> 4, ts = tid & 15;
    for (int pass = 0; pass < 8; ++pass) {
        const int r = pass * 16 + rloc;
        const unsigned short* qrow = qs[r];
        const float* krow = kbl[ts];
        float lb = 0.f;
#pragma unroll 4
        for (int dw = 0; dw < 64; ++dw) {
            unsigned int qv = *(const unsigned int*)&qrow[dw * 2];
            float2 kv = *(const float2*)&krow[dw * 2];
            lb += bf2f((unsigned short)(qv & 0xffff)) * kv.x +
                  bf2f((unsigned short)(qv >> 16)) * kv.y;
        }
        float e = __expf(lb * rms_l[r] - l_l[r]);
        e += __shfl_xor(e, 1);
        e += __shfl_xor(e, 2);
        e += __shfl_xor(e, 4);
        e += __shfl_xor(e, 8);
        if (ts == 0)
            atomicAdd(&out[(size_t)h * S_TOK + m0 + r], 0.25f / (1.0f + e));
    }
}

extern "C" void kernel_launch(void* const* d_in, const int* in_sizes, int n_in,
                              void* d_out, int out_size, void* d_ws, size_t ws_size,
                              hipStream_t stream)
{
    const float* hid = (const float*)d_in[0];
    const float* Wq  = (const float*)d_in[1];
    const float* bq  = (const float*)d_in[2];
    const float* Wk  = (const float*)d_in[3];
    const float* qnw = (const float*)d_in[4];
    const float* knw = (const float*)d_in[5];
    const float* bb  = (const float*)d_in[6];
    const float* kb  = (const float*)d_in[7];
    float* out = (float*)d_out;

    hipMemsetAsync(d_out, 0, (size_t)out_size * sizeof(float), stream);

    const size_t HID_E = (size_t)S_TOK * DIN;          // 67.1M elements
    const size_t WQ_E  = (size_t)NH * NG * DH * DIN;   // 8.4M
    const size_t WK_E  = (size_t)NH * DH * DIN;        // 2.1M

    unsigned short* hid_b = (unsigned short*)d_ws;
    unsigned short* wq_b  = hid_b + HID_E;
    unsigned short* wk_b  = wq_b + WQ_E;
    unsigned short* kn_ws = wk_b + WK_E;

    cvt_bf16_kernel<<<2048, 256, 0, stream>>>(hid, hid_b, (int)(HID_E / 8));
    cvt_bf16_kernel<<<512, 256, 0, stream>>>(Wq, wq_b, (int)(WQ_E / 8));
    cvt_bf16_kernel<<<256, 256, 0, stream>>>(Wk, wk_b, (int)(WK_E / 8));

    // x = head / chunk (fast-varying) so adjacent blocks share the same A-tile
    kproj_bf16<<<dim3(NH, S_TOK / 128), dim3(256), 0, stream>>>(hid_b, wk_b, knw, kn_ws);
    qscore_bf16<<<dim3(NH * NG, S_TOK / 128), dim3(256), 0, stream>>>(hid_b, wq_b, bq, qnw, bb, kb, kn_ws, out);
}

// Round 5
// 977.172 us; speedup vs baseline: 1.9600x; 1.1482x over previous
//
#include <hip/hip_runtime.h>

#define S_TOK 32768
#define DIN   2048
#define NH    8
#define NG    4
#define DH    128
#define NSINK 16
#define BK    64

typedef float        f32x4 __attribute__((ext_vector_type(4)));
typedef short        s16x8 __attribute__((ext_vector_type(8)));
typedef unsigned int u32x4 __attribute__((ext_vector_type(4)));

__device__ __forceinline__ unsigned short f2bf(float f) {
    unsigned int u = __builtin_bit_cast(unsigned int, f);
    u = (u + 0x7fffu + ((u >> 16) & 1u)) >> 16;
    return (unsigned short)u;
}
__device__ __forceinline__ float bf2f(unsigned short h) {
    unsigned int u = ((unsigned int)h) << 16;
    return __builtin_bit_cast(float, u);
}
__device__ __forceinline__ unsigned int pack2(float lo, float hi) {
    return (unsigned int)f2bf(lo) | ((unsigned int)f2bf(hi) << 16);
}

// ---------------- fp32 -> bf16 pre-conversion
__global__ __launch_bounds__(256) void cvt_bf16_kernel(const float* __restrict__ in,
                                                       unsigned short* __restrict__ out,
                                                       int n8)
{
    int i = blockIdx.x * 256 + threadIdx.x;
    const int stride = gridDim.x * 256;
    for (; i < n8; i += stride) {
        const float* p = in + (size_t)i * 8;
        float4 a = *(const float4*)p;
        float4 b = *(const float4*)(p + 4);
        u32x4 v;
        v.x = pack2(a.x, a.y); v.y = pack2(a.z, a.w);
        v.z = pack2(b.x, b.y); v.w = pack2(b.z, b.w);
        *(u32x4*)(out + (size_t)i * 8) = v;
    }
}

// LDS staging layout per buffer (16384 elems): A[128 rows][8 granules], B at +8192.
// Granule slot s of row r holds global granule s ^ (r&7) (pre-swizzled global
// source, linear LDS dest per global_load_lds; read slot = g ^ (r&7)).

// ---------------- Kernel A: k = RMSNorm(hid @ Wk^T)*k_norm_w -> kn_ws bf16 [S][1024]
__global__ __launch_bounds__(256) void kproj_bf16(const unsigned short* __restrict__ hid,
                                                  const unsigned short* __restrict__ Wk,
                                                  const float* __restrict__ knw,
                                                  unsigned short* __restrict__ kn_ws)
{
    __shared__ alignas(16) unsigned short smem[32768];   // 2 staging bufs; qs aliases after loop
    __shared__ float rms_l[128];
    __shared__ float wsm[128];
    unsigned short (*qs)[132] = (unsigned short(*)[132])smem;

    const int tid = threadIdx.x, lane = tid & 63, wv = tid >> 6;
    const int wm = wv >> 1, wn = wv & 1;
    const int h = blockIdx.x, m0 = blockIdx.y * 128;
    if (tid < 128) wsm[tid] = knw[tid];

    const unsigned short* Ab = hid + (size_t)m0 * DIN;
    const unsigned short* Bb = Wk + (size_t)h * DH * DIN;

    f32x4 acc[4][4];
#pragma unroll
    for (int m = 0; m < 4; ++m)
#pragma unroll
        for (int n = 0; n < 4; ++n)
            acc[m][n] = f32x4{0.f, 0.f, 0.f, 0.f};

    const int lr = lane >> 3;
    const int lc = (((lane & 7) ^ lr) * 8);

    auto STAGE = [&](int b, int kt) {
        unsigned short* Ad = smem + b * 16384;
        unsigned short* Bd = Ad + 8192;
#pragma unroll
        for (int i = 0; i < 4; ++i) {
            const int row = wv * 32 + i * 8;
            __builtin_amdgcn_global_load_lds(
                (const __attribute__((address_space(1))) unsigned int*)(Ab + (size_t)(row + lr) * DIN + kt + lc),
                (__attribute__((address_space(3))) unsigned int*)(Ad + row * BK), 16, 0, 0);
            __builtin_amdgcn_global_load_lds(
                (const __attribute__((address_space(1))) unsigned int*)(Bb + (size_t)(row + lr) * DIN + kt + lc),
                (__attribute__((address_space(3))) unsigned int*)(Bd + row * BK), 16, 0, 0);
        }
    };

    STAGE(0, 0);
    __syncthreads();
    for (int t = 0; t < DIN / BK; ++t) {
        const int cur = t & 1;
        if (t < DIN / BK - 1) STAGE(cur ^ 1, (t + 1) * BK);
        const unsigned short* A_ = smem + cur * 16384;
        const unsigned short* B_ = A_ + 8192;
#pragma unroll
        for (int kk = 0; kk < 2; ++kk) {
            s16x8 af[4], bfr[4];
            const int g0 = kk * 4 + (lane >> 4);
            const int slot = (g0 ^ (lane & 7)) * 8;
#pragma unroll
            for (int m = 0; m < 4; ++m)
                af[m] = *(const s16x8*)&A_[(wm * 64 + m * 16 + (lane & 15)) * BK + slot];
#pragma unroll
            for (int n = 0; n < 4; ++n)
                bfr[n] = *(const s16x8*)&B_[(wn * 64 + n * 16 + (lane & 15)) * BK + slot];
#pragma unroll
            for (int m = 0; m < 4; ++m)
#pragma unroll
                for (int n = 0; n < 4; ++n)
                    acc[m][n] = __builtin_amdgcn_mfma_f32_16x16x32_bf16(af[m], bfr[n], acc[m][n], 0, 0, 0);
        }
        __syncthreads();
    }

    // acc -> qs (k_raw bf16). C layout: col = lane&15, row = (lane>>4)*4 + reg.
#pragma unroll
    for (int m = 0; m < 4; ++m)
#pragma unroll
        for (int n = 0; n < 4; ++n)
#pragma unroll
            for (int r = 0; r < 4; ++r)
                qs[wm * 64 + m * 16 + (lane >> 4) * 4 + r][wn * 64 + n * 16 + (lane & 15)] = f2bf(acc[m][n][r]);
    __syncthreads();
    if (tid < 128) {
        const unsigned short* row = qs[tid];
        float s2 = 0.f;
#pragma unroll 4
        for (int dw = 0; dw < 64; ++dw) {
            unsigned int v = *(const unsigned int*)&row[dw * 2];
            float f0 = bf2f((unsigned short)(v & 0xffff));
            float f1 = bf2f((unsigned short)(v >> 16));
            s2 += f0 * f0 + f1 * f1;
        }
        rms_l[tid] = rsqrtf(s2 * (1.0f / 128.0f) + 1e-6f);
    }
    __syncthreads();
    const int rloc = tid >> 4, cb = (tid & 15) * 8;
#pragma unroll
    for (int pass = 0; pass < 8; ++pass) {
        const int r = pass * 16 + rloc;
        const float rq = rms_l[r];
        u32x4 v;
        float f0, f1;
        f0 = bf2f(qs[r][cb + 0]) * rq * wsm[cb + 0];
        f1 = bf2f(qs[r][cb + 1]) * rq * wsm[cb + 1];
        v.x = pack2(f0, f1);
        f0 = bf2f(qs[r][cb + 2]) * rq * wsm[cb + 2];
        f1 = bf2f(qs[r][cb + 3]) * rq * wsm[cb + 3];
        v.y = pack2(f0, f1);
        f0 = bf2f(qs[r][cb + 4]) * rq * wsm[cb + 4];
        f1 = bf2f(qs[r][cb + 5]) * rq * wsm[cb + 5];
        v.z = pack2(f0, f1);
        f0 = bf2f(qs[r][cb + 6]) * rq * wsm[cb + 6];
        f1 = bf2f(qs[r][cb + 7]) * rq * wsm[cb + 7];
        v.w = pack2(f0, f1);
        *(u32x4*)&kn_ws[(size_t)(m0 + r) * (NH * DH) + h * DH + cb] = v;
    }
}

// ---------------- Kernel B: q-proj + RMSNorm + MFMA sink gate -> atomicAdd out
__global__ __launch_bounds__(256) void qscore_bf16(const unsigned short* __restrict__ hid,
                                                   const unsigned short* __restrict__ Wq,
                                                   const float* __restrict__ bq,
                                                   const float* __restrict__ qnw,
                                                   const float* __restrict__ bb,
                                                   const float* __restrict__ kbase,
                                                   const unsigned short* __restrict__ kn_ws,
                                                   float* __restrict__ out)
{
    __shared__ alignas(16) unsigned short smem[32768];   // 2 staging bufs; qs aliases after loop
    __shared__ alignas(16) unsigned short kbn[NSINK][136];  // bf16(k_base * q_norm_w), padded
    __shared__ float rms_l[128];
    __shared__ float l_l[128];
    __shared__ float wsm[128];
    unsigned short (*qs)[132] = (unsigned short(*)[132])smem;

    const int tid = threadIdx.x, lane = tid & 63, wv = tid >> 6;
    const int wm = wv >> 1, wn = wv & 1;
    const int chunk = blockIdx.x;        // h*4+g (chunk-fast for A-tile L2 sharing)
    const int m0 = blockIdx.y * 128;
    const int h = chunk >> 2, g = chunk & 3;
    if (tid < 128) wsm[tid] = qnw[tid];

    // stage bf16(k_base * q_norm_w) -> kbn  (visible after first barrier)
    {
        const int ts = tid >> 4, d0 = (tid & 15) * 8;
        const float* src = kbase + ((size_t)h * NSINK + ts) * DH + d0;
        float4 x = *(const float4*)src;
        float4 y = *(const float4*)(src + 4);
        const float* w = qnw + d0;
        u32x4 v;
        v.x = pack2(x.x * w[0], x.y * w[1]);
        v.y = pack2(x.z * w[2], x.w * w[3]);
        v.z = pack2(y.x * w[4], y.y * w[5]);
        v.w = pack2(y.z * w[6], y.w * w[7]);
        *(u32x4*)&kbn[ts][d0] = v;
    }

    const unsigned short* Ab = hid + (size_t)m0 * DIN;
    const unsigned short* Bb = Wq + (size_t)chunk * DH * DIN;

    f32x4 acc[4][4];
#pragma unroll
    for (int m = 0; m < 4; ++m)
#pragma unroll
        for (int n = 0; n < 4; ++n)
            acc[m][n] = f32x4{0.f, 0.f, 0.f, 0.f};

    const int lr = lane >> 3;
    const int lc = (((lane & 7) ^ lr) * 8);

    auto STAGE = [&](int b, int kt) {
        unsigned short* Ad = smem + b * 16384;
        unsigned short* Bd = Ad + 8192;
#pragma unroll
        for (int i = 0; i < 4; ++i) {
            const int row = wv * 32 + i * 8;
            __builtin_amdgcn_global_load_lds(
                (const __attribute__((address_space(1))) unsigned int*)(Ab + (size_t)(row + lr) * DIN + kt + lc),
                (__attribute__((address_space(3))) unsigned int*)(Ad + row * BK), 16, 0, 0);
            __builtin_amdgcn_global_load_lds(
                (const __attribute__((address_space(1))) unsigned int*)(Bb + (size_t)(row + lr) * DIN + kt + lc),
                (__attribute__((address_space(3))) unsigned int*)(Bd + row * BK), 16, 0, 0);
        }
    };

    STAGE(0, 0);
    __syncthreads();
    for (int t = 0; t < DIN / BK; ++t) {
        const int cur = t & 1;
        if (t < DIN / BK - 1) STAGE(cur ^ 1, (t + 1) * BK);
        const unsigned short* A_ = smem + cur * 16384;
        const unsigned short* B_ = A_ + 8192;
#pragma unroll
        for (int kk = 0; kk < 2; ++kk) {
            s16x8 af[4], bfr[4];
            const int g0 = kk * 4 + (lane >> 4);
            const int slot = (g0 ^ (lane & 7)) * 8;
#pragma unroll
            for (int m = 0; m < 4; ++m)
                af[m] = *(const s16x8*)&A_[(wm * 64 + m * 16 + (lane & 15)) * BK + slot];
#pragma unroll
            for (int n = 0; n < 4; ++n)
                bfr[n] = *(const s16x8*)&B_[(wn * 64 + n * 16 + (lane & 15)) * BK + slot];
#pragma unroll
            for (int m = 0; m < 4; ++m)
#pragma unroll
                for (int n = 0; n < 4; ++n)
                    acc[m][n] = __builtin_amdgcn_mfma_f32_16x16x32_bf16(af[m], bfr[n], acc[m][n], 0, 0, 0);
        }
        __syncthreads();
    }

    // acc + bq -> qs bf16 (q_raw with bias, pre-norm)
    float bqv[4];
#pragma unroll
    for (int n = 0; n < 4; ++n)
        bqv[n] = bq[chunk * DH + wn * 64 + n * 16 + (lane & 15)];
#pragma unroll
    for (int m = 0; m < 4; ++m)
#pragma unroll
        for (int n = 0; n < 4; ++n)
#pragma unroll
            for (int r = 0; r < 4; ++r)
                qs[wm * 64 + m * 16 + (lane >> 4) * 4 + r][wn * 64 + n * 16 + (lane & 15)] =
                    f2bf(acc[m][n][r] + bqv[n]);

    const float bval = 2.0f * bb[h * NG + g];
    __syncthreads();

    // pass2: 2 threads per row; rms + k.q logit (k from L2-resident kn_ws)
    {
        const int r2 = tid >> 1, ch = (tid & 1) * 64;
        const unsigned short* qrow = &qs[r2][ch];
        const unsigned short* kg = kn_ws + (size_t)(m0 + r2) * (NH * DH) + h * DH + ch;
        const float* wp = &wsm[ch];
        float s2 = 0.f, skq = 0.f;
#pragma unroll 2
        for (int i = 0; i < 8; ++i) {
            u32x4 kv = *(const u32x4*)(kg + i * 8);
#pragma unroll
            for (int j = 0; j < 4; ++j) {
                unsigned int qv = *(const unsigned int*)&qrow[i * 8 + j * 2];
                unsigned int kw = kv[j];
                float q0 = bf2f((unsigned short)(qv & 0xffff));
                float q1 = bf2f((unsigned short)(qv >> 16));
                float k0 = bf2f((unsigned short)(kw & 0xffff));
                float k1 = bf2f((unsigned short)(kw >> 16));
                s2  += q0 * q0 + q1 * q1;
                skq += q0 * k0 * wp[i * 8 + j * 2] + q1 * k1 * wp[i * 8 + j * 2 + 1];
            }
        }
        s2  += __shfl_xor(s2, 1);
        skq += __shfl_xor(skq, 1);
        if ((tid & 1) == 0) {
            const float rs = rsqrtf(s2 * (1.0f / 128.0f) + 1e-6f) * 0.08838834764831845f;
            rms_l[r2] = rs;
            l_l[r2]   = skq * rs + bval;
        }
    }
    __syncthreads();

    // pass3 (MFMA): sink logits = q_tile[128x128] @ kbn^T[128x16]; wave wv owns rows [wv*32, wv*32+32)
    {
        f32x4 sacc0 = f32x4{0.f, 0.f, 0.f, 0.f};
        f32x4 sacc1 = f32x4{0.f, 0.f, 0.f, 0.f};
        const int ar = wv * 32 + (lane & 15);
        const int kc = (lane >> 4) * 8;
#pragma unroll
        for (int ks = 0; ks < 4; ++ks) {
            s16x8 bf_ = *(const s16x8*)&kbn[lane & 15][ks * 32 + kc];
            s16x8 a0  = *(const s16x8*)&qs[ar][ks * 32 + kc];
            s16x8 a1  = *(const s16x8*)&qs[ar + 16][ks * 32 + kc];
            sacc0 = __builtin_amdgcn_mfma_f32_16x16x32_bf16(a0, bf_, sacc0, 0, 0, 0);
            sacc1 = __builtin_amdgcn_mfma_f32_16x16x32_bf16(a1, bf_, sacc1, 0, 0, 0);
        }
        // C layout: sink t = lane&15, row = (lane>>4)*4 + r (+ mt*16 + wv*32)
#pragma unroll
        for (int mt = 0; mt < 2; ++mt) {
            f32x4 sa = mt ? sacc1 : sacc0;
#pragma unroll
            for (int r = 0; r < 4; ++r) {
                const int row = wv * 32 + mt * 16 + (lane >> 4) * 4 + r;
                float e = __expf(sa[r] * rms_l[row] - l_l[row]);
                e += __shfl_xor(e, 1);
                e += __shfl_xor(e, 2);
                e += __shfl_xor(e, 4);
                e += __shfl_xor(e, 8);
                if ((lane & 15) == 0)
                    atomicAdd(&out[(size_t)h * S_TOK + m0 + row], 0.25f / (1.0f + e));
            }
        }
    }
}

extern "C" void kernel_launch(void* const* d_in, const int* in_sizes, int n_in,
                              void* d_out, int out_size, void* d_ws, size_t ws_size,
                              hipStream_t stream)
{
    const float* hid = (const float*)d_in[0];
    const float* Wq  = (const float*)d_in[1];
    const float* bq  = (const float*)d_in[2];
    const float* Wk  = (const float*)d_in[3];
    const float* qnw = (const float*)d_in[4];
    const float* knw = (const float*)d_in[5];
    const float* bb  = (const float*)d_in[6];
    const float* kb  = (const float*)d_in[7];
    float* out = (float*)d_out;

    (void)hipMemsetAsync(d_out, 0, (size_t)out_size * sizeof(float), stream);

    const size_t HID_E = (size_t)S_TOK * DIN;
    const size_t WQ_E  = (size_t)NH * NG * DH * DIN;
    const size_t WK_E  = (size_t)NH * DH * DIN;

    unsigned short* hid_b = (unsigned short*)d_ws;
    unsigned short* wq_b  = hid_b + HID_E;
    unsigned short* wk_b  = wq_b + WQ_E;
    unsigned short* kn_ws = wk_b + WK_E;

    cvt_bf16_kernel<<<2048, 256, 0, stream>>>(hid, hid_b, (int)(HID_E / 8));
    cvt_bf16_kernel<<<512, 256, 0, stream>>>(Wq, wq_b, (int)(WQ_E / 8));
    cvt_bf16_kernel<<<256, 256, 0, stream>>>(Wk, wk_b, (int)(WK_E / 8));

    kproj_bf16<<<dim3(NH, S_TOK / 128), dim3(256), 0, stream>>>(hid_b, wk_b, knw, kn_ws);
    qscore_bf16<<<dim3(NH * NG, S_TOK / 128), dim3(256), 0, stream>>>(hid_b, wq_b, bq, qnw, bb, kb, kn_ws, out);
}

// Round 6
// 924.430 us; speedup vs baseline: 2.0718x; 1.0571x over previous
//
#include <hip/hip_runtime.h>

#define S_TOK 32768
#define DIN   2048
#define NH    8
#define NG    4
#define DH    128
#define NSINK 16
#define BK    64

typedef float        f32x4 __attribute__((ext_vector_type(4)));
typedef short        s16x8 __attribute__((ext_vector_type(8)));
typedef unsigned int u32x4 __attribute__((ext_vector_type(4)));

__device__ __forceinline__ unsigned short f2bf(float f) {
    unsigned int u = __builtin_bit_cast(unsigned int, f);
    u = (u + 0x7fffu + ((u >> 16) & 1u)) >> 16;
    return (unsigned short)u;
}
__device__ __forceinline__ float bf2f(unsigned short h) {
    unsigned int u = ((unsigned int)h) << 16;
    return __builtin_bit_cast(float, u);
}
__device__ __forceinline__ unsigned int pack2(float lo, float hi) {
    return (unsigned int)f2bf(lo) | ((unsigned int)f2bf(hi) << 16);
}

// ---------------- fp32 -> bf16 pre-conversion
__global__ __launch_bounds__(256) void cvt_bf16_kernel(const float* __restrict__ in,
                                                       unsigned short* __restrict__ out,
                                                       int n8)
{
    int i = blockIdx.x * 256 + threadIdx.x;
    const int stride = gridDim.x * 256;
    for (; i < n8; i += stride) {
        const float* p = in + (size_t)i * 8;
        float4 a = *(const float4*)p;
        float4 b = *(const float4*)(p + 4);
        u32x4 v;
        v.x = pack2(a.x, a.y); v.y = pack2(a.z, a.w);
        v.z = pack2(b.x, b.y); v.w = pack2(b.z, b.w);
        *(u32x4*)(out + (size_t)i * 8) = v;
    }
}

// LDS staging per buffer (16384 elems): A[128 rows][8 granules], B at +8192.
// Granule slot s of row r holds global granule s ^ (r&7); read slot = g ^ (r&7).
// Buffer select is compile-time (0 / 16384) via 2x-unrolled K loop.

// ---------------- Kernel A: k = RMSNorm(hid @ Wk^T)*k_norm_w -> kn_ws bf16 [S][1024]
__global__ __launch_bounds__(256) void kproj_bf16(const unsigned short* __restrict__ hid,
                                                  const unsigned short* __restrict__ Wk,
                                                  const float* __restrict__ knw,
                                                  unsigned short* __restrict__ kn_ws)
{
    __shared__ alignas(16) unsigned short smem[32768];   // 2 staging bufs; qs aliases after loop
    __shared__ float rms_l[128];
    __shared__ float wsm[128];
    unsigned short (*qs)[132] = (unsigned short(*)[132])smem;

    const int tid = threadIdx.x, lane = tid & 63, wv = tid >> 6;
    const int wm = wv >> 1, wn = wv & 1;
    const int h = blockIdx.x, m0 = blockIdx.y * 128;
    if (tid < 128) wsm[tid] = knw[tid];

    const int lr = lane >> 3;
    const int lc = (((lane & 7) ^ lr) * 8);
    // per-lane 32-bit source offsets (held in VGPRs; base pointers stay uniform/SGPR)
    const int av0 = (wv * 32 + 0  + lr) * DIN + lc;
    const int av1 = (wv * 32 + 8  + lr) * DIN + lc;
    const int av2 = (wv * 32 + 16 + lr) * DIN + lc;
    const int av3 = (wv * 32 + 24 + lr) * DIN + lc;
    // swizzled ds_read base offsets (elements)
    const int rA0 = (wm * 64 + (lane & 15)) * BK + ((lane >> 4) ^ (lane & 7)) * 8;
    const int rA1 = (wm * 64 + (lane & 15)) * BK + (((lane >> 4) + 4) ^ (lane & 7)) * 8;
    const int rB0 = (wn * 64 + (lane & 15)) * BK + ((lane >> 4) ^ (lane & 7)) * 8;
    const int rB1 = (wn * 64 + (lane & 15)) * BK + (((lane >> 4) + 4) ^ (lane & 7)) * 8;

    const unsigned short* aP = hid + (size_t)m0 * DIN;   // uniform; advances by BK
    const unsigned short* bP = Wk + (size_t)h * DH * DIN;

    f32x4 acc[4][4];
#pragma unroll
    for (int m = 0; m < 4; ++m)
#pragma unroll
        for (int n = 0; n < 4; ++n)
            acc[m][n] = f32x4{0.f, 0.f, 0.f, 0.f};

    auto STAGE = [&](int ldsBase, const unsigned short* aS, const unsigned short* bS) {
#pragma unroll
        for (int i = 0; i < 4; ++i) {
            const int ao = (i == 0) ? av0 : (i == 1) ? av1 : (i == 2) ? av2 : av3;
            __builtin_amdgcn_global_load_lds(
                (const __attribute__((address_space(1))) unsigned int*)(aS + ao),
                (__attribute__((address_space(3))) unsigned int*)(smem + ldsBase + (wv * 32 + i * 8) * BK), 16, 0, 0);
            __builtin_amdgcn_global_load_lds(
                (const __attribute__((address_space(1))) unsigned int*)(bS + ao),
                (__attribute__((address_space(3))) unsigned int*)(smem + ldsBase + 8192 + (wv * 32 + i * 8) * BK), 16, 0, 0);
        }
    };
    auto COMPUTE = [&](int base) {
#pragma unroll
        for (int kk = 0; kk < 2; ++kk) {
            const int sA = base + (kk ? rA1 : rA0);
            const int sB = base + 8192 + (kk ? rB1 : rB0);
            s16x8 af[4], bfr[4];
#pragma unroll
            for (int m = 0; m < 4; ++m) af[m] = *(const s16x8*)&smem[sA + m * 1024];
#pragma unroll
            for (int n = 0; n < 4; ++n) bfr[n] = *(const s16x8*)&smem[sB + n * 1024];
#pragma unroll
            for (int m = 0; m < 4; ++m)
#pragma unroll
                for (int n = 0; n < 4; ++n)
                    acc[m][n] = __builtin_amdgcn_mfma_f32_16x16x32_bf16(af[m], bfr[n], acc[m][n], 0, 0, 0);
        }
    };

    STAGE(0, aP, bP);
    __syncthreads();
    for (int kt = 0; kt < DIN; kt += 2 * BK) {
        aP += BK; bP += BK;
        STAGE(16384, aP, bP);       // tile kt+64 -> buf1 (kt+64 < DIN always here)
        COMPUTE(0);                 // tile kt from buf0
        __syncthreads();
        aP += BK; bP += BK;
        if (kt + 2 * BK < DIN) STAGE(0, aP, bP);   // tile kt+128 -> buf0
        COMPUTE(16384);             // tile kt+64 from buf1
        __syncthreads();
    }

    // acc -> qs (k_raw bf16). C layout: col = lane&15, row = (lane>>4)*4 + reg.
#pragma unroll
    for (int m = 0; m < 4; ++m)
#pragma unroll
        for (int n = 0; n < 4; ++n)
#pragma unroll
            for (int r = 0; r < 4; ++r)
                qs[wm * 64 + m * 16 + (lane >> 4) * 4 + r][wn * 64 + n * 16 + (lane & 15)] = f2bf(acc[m][n][r]);
    __syncthreads();
    if (tid < 128) {
        const unsigned short* row = qs[tid];
        float s2 = 0.f;
#pragma unroll 4
        for (int dw = 0; dw < 64; ++dw) {
            unsigned int v = *(const unsigned int*)&row[dw * 2];
            float f0 = bf2f((unsigned short)(v & 0xffff));
            float f1 = bf2f((unsigned short)(v >> 16));
            s2 += f0 * f0 + f1 * f1;
        }
        rms_l[tid] = rsqrtf(s2 * (1.0f / 128.0f) + 1e-6f);
    }
    __syncthreads();
    const int rloc = tid >> 4, cb = (tid & 15) * 8;
#pragma unroll
    for (int pass = 0; pass < 8; ++pass) {
        const int r = pass * 16 + rloc;
        const float rq = rms_l[r];
        u32x4 v;
        float f0, f1;
        f0 = bf2f(qs[r][cb + 0]) * rq * wsm[cb + 0];
        f1 = bf2f(qs[r][cb + 1]) * rq * wsm[cb + 1];
        v.x = pack2(f0, f1);
        f0 = bf2f(qs[r][cb + 2]) * rq * wsm[cb + 2];
        f1 = bf2f(qs[r][cb + 3]) * rq * wsm[cb + 3];
        v.y = pack2(f0, f1);
        f0 = bf2f(qs[r][cb + 4]) * rq * wsm[cb + 4];
        f1 = bf2f(qs[r][cb + 5]) * rq * wsm[cb + 5];
        v.z = pack2(f0, f1);
        f0 = bf2f(qs[r][cb + 6]) * rq * wsm[cb + 6];
        f1 = bf2f(qs[r][cb + 7]) * rq * wsm[cb + 7];
        v.w = pack2(f0, f1);
        *(u32x4*)&kn_ws[(size_t)(m0 + r) * (NH * DH) + h * DH + cb] = v;
    }
}

// ---------------- Kernel B: q-proj + RMSNorm + MFMA sink gate -> atomicAdd out
__global__ __launch_bounds__(256) void qscore_bf16(const unsigned short* __restrict__ hid,
                                                   const unsigned short* __restrict__ Wq,
                                                   const float* __restrict__ bq,
                                                   const float* __restrict__ qnw,
                                                   const float* __restrict__ bb,
                                                   const float* __restrict__ kbase,
                                                   const unsigned short* __restrict__ kn_ws,
                                                   float* __restrict__ out)
{
    __shared__ alignas(16) unsigned short smem[32768];      // 2 staging bufs; qs aliases after loop
    __shared__ alignas(16) unsigned short kbn[NSINK][136];  // bf16(k_base * q_norm_w), padded
    __shared__ float rms_l[128];
    __shared__ float l_l[128];
    __shared__ float wsm[128];
    unsigned short (*qs)[132] = (unsigned short(*)[132])smem;

    const int tid = threadIdx.x, lane = tid & 63, wv = tid >> 6;
    const int wm = wv >> 1, wn = wv & 1;
    const int chunk = blockIdx.x;        // h*4+g (chunk-fast for A-tile L2 sharing)
    const int m0 = blockIdx.y * 128;
    const int h = chunk >> 2, g = chunk & 3;
    if (tid < 128) wsm[tid] = qnw[tid];

    // stage bf16(k_base * q_norm_w) -> kbn  (visible after first barrier)
    {
        const int ts = tid >> 4, d0 = (tid & 15) * 8;
        const float* src = kbase + ((size_t)h * NSINK + ts) * DH + d0;
        float4 x = *(const float4*)src;
        float4 y = *(const float4*)(src + 4);
        const float* w = qnw + d0;
        u32x4 v;
        v.x = pack2(x.x * w[0], x.y * w[1]);
        v.y = pack2(x.z * w[2], x.w * w[3]);
        v.z = pack2(y.x * w[4], y.y * w[5]);
        v.w = pack2(y.z * w[6], y.w * w[7]);
        *(u32x4*)&kbn[ts][d0] = v;
    }

    const int lr = lane >> 3;
    const int lc = (((lane & 7) ^ lr) * 8);
    const int av0 = (wv * 32 + 0  + lr) * DIN + lc;
    const int av1 = (wv * 32 + 8  + lr) * DIN + lc;
    const int av2 = (wv * 32 + 16 + lr) * DIN + lc;
    const int av3 = (wv * 32 + 24 + lr) * DIN + lc;
    const int rA0 = (wm * 64 + (lane & 15)) * BK + ((lane >> 4) ^ (lane & 7)) * 8;
    const int rA1 = (wm * 64 + (lane & 15)) * BK + (((lane >> 4) + 4) ^ (lane & 7)) * 8;
    const int rB0 = (wn * 64 + (lane & 15)) * BK + ((lane >> 4) ^ (lane & 7)) * 8;
    const int rB1 = (wn * 64 + (lane & 15)) * BK + (((lane >> 4) + 4) ^ (lane & 7)) * 8;

    const unsigned short* aP = hid + (size_t)m0 * DIN;
    const unsigned short* bP = Wq + (size_t)chunk * DH * DIN;

    f32x4 acc[4][4];
#pragma unroll
    for (int m = 0; m < 4; ++m)
#pragma unroll
        for (int n = 0; n < 4; ++n)
            acc[m][n] = f32x4{0.f, 0.f, 0.f, 0.f};

    auto STAGE = [&](int ldsBase, const unsigned short* aS, const unsigned short* bS) {
#pragma unroll
        for (int i = 0; i < 4; ++i) {
            const int ao = (i == 0) ? av0 : (i == 1) ? av1 : (i == 2) ? av2 : av3;
            __builtin_amdgcn_global_load_lds(
                (const __attribute__((address_space(1))) unsigned int*)(aS + ao),
                (__attribute__((address_space(3))) unsigned int*)(smem + ldsBase + (wv * 32 + i * 8) * BK), 16, 0, 0);
            __builtin_amdgcn_global_load_lds(
                (const __attribute__((address_space(1))) unsigned int*)(bS + ao),
                (__attribute__((address_space(3))) unsigned int*)(smem + ldsBase + 8192 + (wv * 32 + i * 8) * BK), 16, 0, 0);
        }
    };
    auto COMPUTE = [&](int base) {
#pragma unroll
        for (int kk = 0; kk < 2; ++kk) {
            const int sA = base + (kk ? rA1 : rA0);
            const int sB = base + 8192 + (kk ? rB1 : rB0);
            s16x8 af[4], bfr[4];
#pragma unroll
            for (int m = 0; m < 4; ++m) af[m] = *(const s16x8*)&smem[sA + m * 1024];
#pragma unroll
            for (int n = 0; n < 4; ++n) bfr[n] = *(const s16x8*)&smem[sB + n * 1024];
#pragma unroll
            for (int m = 0; m < 4; ++m)
#pragma unroll
                for (int n = 0; n < 4; ++n)
                    acc[m][n] = __builtin_amdgcn_mfma_f32_16x16x32_bf16(af[m], bfr[n], acc[m][n], 0, 0, 0);
        }
    };

    STAGE(0, aP, bP);
    __syncthreads();
    for (int kt = 0; kt < DIN; kt += 2 * BK) {
        aP += BK; bP += BK;
        STAGE(16384, aP, bP);
        COMPUTE(0);
        __syncthreads();
        aP += BK; bP += BK;
        if (kt + 2 * BK < DIN) STAGE(0, aP, bP);
        COMPUTE(16384);
        __syncthreads();
    }

    // acc + bq -> qs bf16 (q_raw with bias, pre-norm)
    float bqv[4];
#pragma unroll
    for (int n = 0; n < 4; ++n)
        bqv[n] = bq[chunk * DH + wn * 64 + n * 16 + (lane & 15)];
#pragma unroll
    for (int m = 0; m < 4; ++m)
#pragma unroll
        for (int n = 0; n < 4; ++n)
#pragma unroll
            for (int r = 0; r < 4; ++r)
                qs[wm * 64 + m * 16 + (lane >> 4) * 4 + r][wn * 64 + n * 16 + (lane & 15)] =
                    f2bf(acc[m][n][r] + bqv[n]);

    const float bval = 2.0f * bb[h * NG + g];
    __syncthreads();

    // pass2: 2 threads per row; rms + k.q logit (k from L2-resident kn_ws)
    {
        const int r2 = tid >> 1, ch = (tid & 1) * 64;
        const unsigned short* qrow = &qs[r2][ch];
        const unsigned short* kg = kn_ws + (size_t)(m0 + r2) * (NH * DH) + h * DH + ch;
        const float* wp = &wsm[ch];
        float s2 = 0.f, skq = 0.f;
#pragma unroll 2
        for (int i = 0; i < 8; ++i) {
            u32x4 kv = *(const u32x4*)(kg + i * 8);
#pragma unroll
            for (int j = 0; j < 4; ++j) {
                unsigned int qv = *(const unsigned int*)&qrow[i * 8 + j * 2];
                unsigned int kw = kv[j];
                float q0 = bf2f((unsigned short)(qv & 0xffff));
                float q1 = bf2f((unsigned short)(qv >> 16));
                float k0 = bf2f((unsigned short)(kw & 0xffff));
                float k1 = bf2f((unsigned short)(kw >> 16));
                s2  += q0 * q0 + q1 * q1;
                skq += q0 * k0 * wp[i * 8 + j * 2] + q1 * k1 * wp[i * 8 + j * 2 + 1];
            }
        }
        s2  += __shfl_xor(s2, 1);
        skq += __shfl_xor(skq, 1);
        if ((tid & 1) == 0) {
            const float rs = rsqrtf(s2 * (1.0f / 128.0f) + 1e-6f) * 0.08838834764831845f;
            rms_l[r2] = rs;
            l_l[r2]   = skq * rs + bval;
        }
    }
    __syncthreads();

    // pass3 (MFMA): sink logits = q_tile[128x128] @ kbn^T[128x16]; wave wv owns rows [wv*32, wv*32+32)
    {
        f32x4 sacc0 = f32x4{0.f, 0.f, 0.f, 0.f};
        f32x4 sacc1 = f32x4{0.f, 0.f, 0.f, 0.f};
        const int ar = wv * 32 + (lane & 15);
        const int kc = (lane >> 4) * 8;
#pragma unroll
        for (int ks = 0; ks < 4; ++ks) {
            s16x8 bf_ = *(const s16x8*)&kbn[lane & 15][ks * 32 + kc];
            s16x8 a0  = *(const s16x8*)&qs[ar][ks * 32 + kc];
            s16x8 a1  = *(const s16x8*)&qs[ar + 16][ks * 32 + kc];
            sacc0 = __builtin_amdgcn_mfma_f32_16x16x32_bf16(a0, bf_, sacc0, 0, 0, 0);
            sacc1 = __builtin_amdgcn_mfma_f32_16x16x32_bf16(a1, bf_, sacc1, 0, 0, 0);
        }
        // C layout: sink t = lane&15, row = (lane>>4)*4 + r (+ mt*16 + wv*32)
#pragma unroll
        for (int mt = 0; mt < 2; ++mt) {
            f32x4 sa = mt ? sacc1 : sacc0;
#pragma unroll
            for (int r = 0; r < 4; ++r) {
                const int row = wv * 32 + mt * 16 + (lane >> 4) * 4 + r;
                float e = __expf(sa[r] * rms_l[row] - l_l[row]);
                e += __shfl_xor(e, 1);
                e += __shfl_xor(e, 2);
                e += __shfl_xor(e, 4);
                e += __shfl_xor(e, 8);
                if ((lane & 15) == 0)
                    atomicAdd(&out[(size_t)h * S_TOK + m0 + row], 0.25f / (1.0f + e));
            }
        }
    }
}

extern "C" void kernel_launch(void* const* d_in, const int* in_sizes, int n_in,
                              void* d_out, int out_size, void* d_ws, size_t ws_size,
                              hipStream_t stream)
{
    const float* hid = (const float*)d_in[0];
    const float* Wq  = (const float*)d_in[1];
    const float* bq  = (const float*)d_in[2];
    const float* Wk  = (const float*)d_in[3];
    const float* qnw = (const float*)d_in[4];
    const float* knw = (const float*)d_in[5];
    const float* bb  = (const float*)d_in[6];
    const float* kb  = (const float*)d_in[7];
    float* out = (float*)d_out;

    (void)hipMemsetAsync(d_out, 0, (size_t)out_size * sizeof(float), stream);

    const size_t HID_E = (size_t)S_TOK * DIN;
    const size_t WQ_E  = (size_t)NH * NG * DH * DIN;
    const size_t WK_E  = (size_t)NH * DH * DIN;

    unsigned short* hid_b = (unsigned short*)d_ws;
    unsigned short* wq_b  = hid_b + HID_E;
    unsigned short* wk_b  = wq_b + WQ_E;
    unsigned short* kn_ws = wk_b + WK_E;

    cvt_bf16_kernel<<<2048, 256, 0, stream>>>(hid, hid_b, (int)(HID_E / 8));
    cvt_bf16_kernel<<<512, 256, 0, stream>>>(Wq, wq_b, (int)(WQ_E / 8));
    cvt_bf16_kernel<<<256, 256, 0, stream>>>(Wk, wk_b, (int)(WK_E / 8));

    kproj_bf16<<<dim3(NH, S_TOK / 128), dim3(256), 0, stream>>>(hid_b, wk_b, knw, kn_ws);
    qscore_bf16<<<dim3(NH * NG, S_TOK / 128), dim3(256), 0, stream>>>(hid_b, wq_b, bq, qnw, bb, kb, kn_ws, out);
}

// Round 7
// 903.592 us; speedup vs baseline: 2.1196x; 1.0231x over previous
//
#include <hip/hip_runtime.h>

#define S_TOK 32768
#define DIN   2048
#define NH    8
#define NG    4
#define DH    128
#define NSINK 16
#define BK    64

typedef float        f32x4 __attribute__((ext_vector_type(4)));
typedef short        s16x8 __attribute__((ext_vector_type(8)));
typedef unsigned int u32x4 __attribute__((ext_vector_type(4)));

__device__ __forceinline__ unsigned short f2bf(float f) {
    unsigned int u = __builtin_bit_cast(unsigned int, f);
    u = (u + 0x7fffu + ((u >> 16) & 1u)) >> 16;
    return (unsigned short)u;
}
__device__ __forceinline__ float bf2f(unsigned short h) {
    unsigned int u = ((unsigned int)h) << 16;
    return __builtin_bit_cast(float, u);
}
__device__ __forceinline__ unsigned int pack2(float lo, float hi) {
    return (unsigned int)f2bf(lo) | ((unsigned int)f2bf(hi) << 16);
}

// ---------------- fp32 -> bf16 pre-conversion
__global__ __launch_bounds__(256) void cvt_bf16_kernel(const float* __restrict__ in,
                                                       unsigned short* __restrict__ out,
                                                       int n8)
{
    int i = blockIdx.x * 256 + threadIdx.x;
    const int stride = gridDim.x * 256;
    for (; i < n8; i += stride) {
        const float* p = in + (size_t)i * 8;
        float4 a = *(const float4*)p;
        float4 b = *(const float4*)(p + 4);
        u32x4 v;
        v.x = pack2(a.x, a.y); v.y = pack2(a.z, a.w);
        v.z = pack2(b.x, b.y); v.w = pack2(b.z, b.w);
        *(u32x4*)(out + (size_t)i * 8) = v;
    }
}

// LDS staging (single buffer, m97-style): A[128 rows][8 granules] at 0, B at +8192 elems.
// Granule slot s of row r holds global granule s ^ (r&7); read slot = g ^ (r&7).
// Single buffer -> ~39 KB LDS -> 4 blocks/CU; cross-block TLP hides the barrier drain.

// ---------------- Kernel A: k = RMSNorm(hid @ Wk^T)*k_norm_w -> kn_ws bf16 [S][1024]
__global__ __launch_bounds__(256) void kproj_bf16(const unsigned short* __restrict__ hid,
                                                  const unsigned short* __restrict__ Wk,
                                                  const float* __restrict__ knw,
                                                  unsigned short* __restrict__ kn_ws)
{
    __shared__ alignas(16) unsigned short smem[16896];   // staging 16384; qs (128x132) aliases
    __shared__ float rms_l[128];
    __shared__ float wsm[128];
    unsigned short (*qs)[132] = (unsigned short(*)[132])smem;

    const int tid = threadIdx.x, lane = tid & 63, wv = tid >> 6;
    const int wm = wv >> 1, wn = wv & 1;
    const int h = blockIdx.x, m0 = blockIdx.y * 128;
    if (tid < 128) wsm[tid] = knw[tid];

    const int lr = lane >> 3;
    const int lc = (((lane & 7) ^ lr) * 8);
    const int av0 = (wv * 32 + 0  + lr) * DIN + lc;
    const int av1 = (wv * 32 + 8  + lr) * DIN + lc;
    const int av2 = (wv * 32 + 16 + lr) * DIN + lc;
    const int av3 = (wv * 32 + 24 + lr) * DIN + lc;
    const int rA0 = (wm * 64 + (lane & 15)) * BK + ((lane >> 4) ^ (lane & 7)) * 8;
    const int rA1 = (wm * 64 + (lane & 15)) * BK + (((lane >> 4) + 4) ^ (lane & 7)) * 8;
    const int rB0 = (wn * 64 + (lane & 15)) * BK + ((lane >> 4) ^ (lane & 7)) * 8;
    const int rB1 = (wn * 64 + (lane & 15)) * BK + (((lane >> 4) + 4) ^ (lane & 7)) * 8;

    const unsigned short* aP = hid + (size_t)m0 * DIN;   // uniform; advances by BK
    const unsigned short* bP = Wk + (size_t)h * DH * DIN;

    f32x4 acc[4][4];
#pragma unroll
    for (int m = 0; m < 4; ++m)
#pragma unroll
        for (int n = 0; n < 4; ++n)
            acc[m][n] = f32x4{0.f, 0.f, 0.f, 0.f};

    for (int kt = 0; kt < DIN; kt += BK) {
#pragma unroll
        for (int i = 0; i < 4; ++i) {
            const int ao = (i == 0) ? av0 : (i == 1) ? av1 : (i == 2) ? av2 : av3;
            __builtin_amdgcn_global_load_lds(
                (const __attribute__((address_space(1))) unsigned int*)(aP + ao),
                (__attribute__((address_space(3))) unsigned int*)(smem + (wv * 32 + i * 8) * BK), 16, 0, 0);
            __builtin_amdgcn_global_load_lds(
                (const __attribute__((address_space(1))) unsigned int*)(bP + ao),
                (__attribute__((address_space(3))) unsigned int*)(smem + 8192 + (wv * 32 + i * 8) * BK), 16, 0, 0);
        }
        __syncthreads();
#pragma unroll
        for (int kk = 0; kk < 2; ++kk) {
            const int sA = (kk ? rA1 : rA0);
            const int sB = 8192 + (kk ? rB1 : rB0);
            s16x8 af[4], bfr[4];
#pragma unroll
            for (int m = 0; m < 4; ++m) af[m] = *(const s16x8*)&smem[sA + m * 1024];
#pragma unroll
            for (int n = 0; n < 4; ++n) bfr[n] = *(const s16x8*)&smem[sB + n * 1024];
#pragma unroll
            for (int m = 0; m < 4; ++m)
#pragma unroll
                for (int n = 0; n < 4; ++n)
                    acc[m][n] = __builtin_amdgcn_mfma_f32_16x16x32_bf16(af[m], bfr[n], acc[m][n], 0, 0, 0);
        }
        __syncthreads();
        aP += BK; bP += BK;
    }

    // acc -> qs (k_raw bf16). C layout: col = lane&15, row = (lane>>4)*4 + reg.
#pragma unroll
    for (int m = 0; m < 4; ++m)
#pragma unroll
        for (int n = 0; n < 4; ++n)
#pragma unroll
            for (int r = 0; r < 4; ++r)
                qs[wm * 64 + m * 16 + (lane >> 4) * 4 + r][wn * 64 + n * 16 + (lane & 15)] = f2bf(acc[m][n][r]);
    __syncthreads();
    if (tid < 128) {
        const unsigned short* row = qs[tid];
        float s2 = 0.f;
#pragma unroll 4
        for (int dw = 0; dw < 64; ++dw) {
            unsigned int v = *(const unsigned int*)&row[dw * 2];
            float f0 = bf2f((unsigned short)(v & 0xffff));
            float f1 = bf2f((unsigned short)(v >> 16));
            s2 += f0 * f0 + f1 * f1;
        }
        rms_l[tid] = rsqrtf(s2 * (1.0f / 128.0f) + 1e-6f);
    }
    __syncthreads();
    const int rloc = tid >> 4, cb = (tid & 15) * 8;
#pragma unroll
    for (int pass = 0; pass < 8; ++pass) {
        const int r = pass * 16 + rloc;
        const float rq = rms_l[r];
        u32x4 v;
        float f0, f1;
        f0 = bf2f(qs[r][cb + 0]) * rq * wsm[cb + 0];
        f1 = bf2f(qs[r][cb + 1]) * rq * wsm[cb + 1];
        v.x = pack2(f0, f1);
        f0 = bf2f(qs[r][cb + 2]) * rq * wsm[cb + 2];
        f1 = bf2f(qs[r][cb + 3]) * rq * wsm[cb + 3];
        v.y = pack2(f0, f1);
        f0 = bf2f(qs[r][cb + 4]) * rq * wsm[cb + 4];
        f1 = bf2f(qs[r][cb + 5]) * rq * wsm[cb + 5];
        v.z = pack2(f0, f1);
        f0 = bf2f(qs[r][cb + 6]) * rq * wsm[cb + 6];
        f1 = bf2f(qs[r][cb + 7]) * rq * wsm[cb + 7];
        v.w = pack2(f0, f1);
        *(u32x4*)&kn_ws[(size_t)(m0 + r) * (NH * DH) + h * DH + cb] = v;
    }
}

// ---------------- Kernel B: q-proj + RMSNorm + MFMA sink gate -> atomicAdd out
__global__ __launch_bounds__(256) void qscore_bf16(const unsigned short* __restrict__ hid,
                                                   const unsigned short* __restrict__ Wq,
                                                   const float* __restrict__ bq,
                                                   const float* __restrict__ qnw,
                                                   const float* __restrict__ bb,
                                                   const float* __restrict__ kbase,
                                                   const unsigned short* __restrict__ kn_ws,
                                                   float* __restrict__ out)
{
    __shared__ alignas(16) unsigned short smem[16896];      // staging 16384; qs (128x132) aliases
    __shared__ alignas(16) unsigned short kbn[NSINK][136];  // bf16(k_base * q_norm_w), padded
    __shared__ float rms_l[128];
    __shared__ float l_l[128];
    __shared__ float wsm[128];
    unsigned short (*qs)[132] = (unsigned short(*)[132])smem;

    const int tid = threadIdx.x, lane = tid & 63, wv = tid >> 6;
    const int wm = wv >> 1, wn = wv & 1;
    const int chunk = blockIdx.x;        // h*4+g (chunk-fast for A-tile L2 sharing)
    const int m0 = blockIdx.y * 128;
    const int h = chunk >> 2, g = chunk & 3;
    if (tid < 128) wsm[tid] = qnw[tid];

    // stage bf16(k_base * q_norm_w) -> kbn  (visible after first barrier)
    {
        const int ts = tid >> 4, d0 = (tid & 15) * 8;
        const float* src = kbase + ((size_t)h * NSINK + ts) * DH + d0;
        float4 x = *(const float4*)src;
        float4 y = *(const float4*)(src + 4);
        const float* w = qnw + d0;
        u32x4 v;
        v.x = pack2(x.x * w[0], x.y * w[1]);
        v.y = pack2(x.z * w[2], x.w * w[3]);
        v.z = pack2(y.x * w[4], y.y * w[5]);
        v.w = pack2(y.z * w[6], y.w * w[7]);
        *(u32x4*)&kbn[ts][d0] = v;
    }

    const int lr = lane >> 3;
    const int lc = (((lane & 7) ^ lr) * 8);
    const int av0 = (wv * 32 + 0  + lr) * DIN + lc;
    const int av1 = (wv * 32 + 8  + lr) * DIN + lc;
    const int av2 = (wv * 32 + 16 + lr) * DIN + lc;
    const int av3 = (wv * 32 + 24 + lr) * DIN + lc;
    const int rA0 = (wm * 64 + (lane & 15)) * BK + ((lane >> 4) ^ (lane & 7)) * 8;
    const int rA1 = (wm * 64 + (lane & 15)) * BK + (((lane >> 4) + 4) ^ (lane & 7)) * 8;
    const int rB0 = (wn * 64 + (lane & 15)) * BK + ((lane >> 4) ^ (lane & 7)) * 8;
    const int rB1 = (wn * 64 + (lane & 15)) * BK + (((lane >> 4) + 4) ^ (lane & 7)) * 8;

    const unsigned short* aP = hid + (size_t)m0 * DIN;
    const unsigned short* bP = Wq + (size_t)chunk * DH * DIN;

    f32x4 acc[4][4];
#pragma unroll
    for (int m = 0; m < 4; ++m)
#pragma unroll
        for (int n = 0; n < 4; ++n)
            acc[m][n] = f32x4{0.f, 0.f, 0.f, 0.f};

    for (int kt = 0; kt < DIN; kt += BK) {
#pragma unroll
        for (int i = 0; i < 4; ++i) {
            const int ao = (i == 0) ? av0 : (i == 1) ? av1 : (i == 2) ? av2 : av3;
            __builtin_amdgcn_global_load_lds(
                (const __attribute__((address_space(1))) unsigned int*)(aP + ao),
                (__attribute__((address_space(3))) unsigned int*)(smem + (wv * 32 + i * 8) * BK), 16, 0, 0);
            __builtin_amdgcn_global_load_lds(
                (const __attribute__((address_space(1))) unsigned int*)(bP + ao),
                (__attribute__((address_space(3))) unsigned int*)(smem + 8192 + (wv * 32 + i * 8) * BK), 16, 0, 0);
        }
        __syncthreads();
#pragma unroll
        for (int kk = 0; kk < 2; ++kk) {
            const int sA = (kk ? rA1 : rA0);
            const int sB = 8192 + (kk ? rB1 : rB0);
            s16x8 af[4], bfr[4];
#pragma unroll
            for (int m = 0; m < 4; ++m) af[m] = *(const s16x8*)&smem[sA + m * 1024];
#pragma unroll
            for (int n = 0; n < 4; ++n) bfr[n] = *(const s16x8*)&smem[sB + n * 1024];
#pragma unroll
            for (int m = 0; m < 4; ++m)
#pragma unroll
                for (int n = 0; n < 4; ++n)
                    acc[m][n] = __builtin_amdgcn_mfma_f32_16x16x32_bf16(af[m], bfr[n], acc[m][n], 0, 0, 0);
        }
        __syncthreads();
        aP += BK; bP += BK;
    }

    // acc + bq -> qs bf16 (q_raw with bias, pre-norm)
    float bqv[4];
#pragma unroll
    for (int n = 0; n < 4; ++n)
        bqv[n] = bq[chunk * DH + wn * 64 + n * 16 + (lane & 15)];
#pragma unroll
    for (int m = 0; m < 4; ++m)
#pragma unroll
        for (int n = 0; n < 4; ++n)
#pragma unroll
            for (int r = 0; r < 4; ++r)
                qs[wm * 64 + m * 16 + (lane >> 4) * 4 + r][wn * 64 + n * 16 + (lane & 15)] =
                    f2bf(acc[m][n][r] + bqv[n]);

    const float bval = 2.0f * bb[h * NG + g];
    __syncthreads();

    // pass2: 2 threads per row; rms + k.q logit (k from L2-resident kn_ws)
    {
        const int r2 = tid >> 1, ch = (tid & 1) * 64;
        const unsigned short* qrow = &qs[r2][ch];
        const unsigned short* kg = kn_ws + (size_t)(m0 + r2) * (NH * DH) + h * DH + ch;
        const float* wp = &wsm[ch];
        float s2 = 0.f, skq = 0.f;
#pragma unroll 2
        for (int i = 0; i < 8; ++i) {
            u32x4 kv = *(const u32x4*)(kg + i * 8);
#pragma unroll
            for (int j = 0; j < 4; ++j) {
                unsigned int qv = *(const unsigned int*)&qrow[i * 8 + j * 2];
                unsigned int kw = kv[j];
                float q0 = bf2f((unsigned short)(qv & 0xffff));
                float q1 = bf2f((unsigned short)(qv >> 16));
                float k0 = bf2f((unsigned short)(kw & 0xffff));
                float k1 = bf2f((unsigned short)(kw >> 16));
                s2  += q0 * q0 + q1 * q1;
                skq += q0 * k0 * wp[i * 8 + j * 2] + q1 * k1 * wp[i * 8 + j * 2 + 1];
            }
        }
        s2  += __shfl_xor(s2, 1);
        skq += __shfl_xor(skq, 1);
        if ((tid & 1) == 0) {
            const float rs = rsqrtf(s2 * (1.0f / 128.0f) + 1e-6f) * 0.08838834764831845f;
            rms_l[r2] = rs;
            l_l[r2]   = skq * rs + bval;
        }
    }
    __syncthreads();

    // pass3 (MFMA): sink logits = q_tile[128x128] @ kbn^T[128x16]; wave wv owns rows [wv*32, wv*32+32)
    {
        f32x4 sacc0 = f32x4{0.f, 0.f, 0.f, 0.f};
        f32x4 sacc1 = f32x4{0.f, 0.f, 0.f, 0.f};
        const int ar = wv * 32 + (lane & 15);
        const int kc = (lane >> 4) * 8;
#pragma unroll
        for (int ks = 0; ks < 4; ++ks) {
            s16x8 bf_ = *(const s16x8*)&kbn[lane & 15][ks * 32 + kc];
            s16x8 a0  = *(const s16x8*)&qs[ar][ks * 32 + kc];
            s16x8 a1  = *(const s16x8*)&qs[ar + 16][ks * 32 + kc];
            sacc0 = __builtin_amdgcn_mfma_f32_16x16x32_bf16(a0, bf_, sacc0, 0, 0, 0);
            sacc1 = __builtin_amdgcn_mfma_f32_16x16x32_bf16(a1, bf_, sacc1, 0, 0, 0);
        }
        // C layout: sink t = lane&15, row = (lane>>4)*4 + r (+ mt*16 + wv*32)
#pragma unroll
        for (int mt = 0; mt < 2; ++mt) {
            f32x4 sa = mt ? sacc1 : sacc0;
#pragma unroll
            for (int r = 0; r < 4; ++r) {
                const int row = wv * 32 + mt * 16 + (lane >> 4) * 4 + r;
                float e = __expf(sa[r] * rms_l[row] - l_l[row]);
                e += __shfl_xor(e, 1);
                e += __shfl_xor(e, 2);
                e += __shfl_xor(e, 4);
                e += __shfl_xor(e, 8);
                if ((lane & 15) == 0)
                    atomicAdd(&out[(size_t)h * S_TOK + m0 + row], 0.25f / (1.0f + e));
            }
        }
    }
}

extern "C" void kernel_launch(void* const* d_in, const int* in_sizes, int n_in,
                              void* d_out, int out_size, void* d_ws, size_t ws_size,
                              hipStream_t stream)
{
    const float* hid = (const float*)d_in[0];
    const float* Wq  = (const float*)d_in[1];
    const float* bq  = (const float*)d_in[2];
    const float* Wk  = (const float*)d_in[3];
    const float* qnw = (const float*)d_in[4];
    const float* knw = (const float*)d_in[5];
    const float* bb  = (const float*)d_in[6];
    const float* kb  = (const float*)d_in[7];
    float* out = (float*)d_out;

    (void)hipMemsetAsync(d_out, 0, (size_t)out_size * sizeof(float), stream);

    const size_t HID_E = (size_t)S_TOK * DIN;
    const size_t WQ_E  = (size_t)NH * NG * DH * DIN;
    const size_t WK_E  = (size_t)NH * DH * DIN;

    unsigned short* hid_b = (unsigned short*)d_ws;
    unsigned short* wq_b  = hid_b + HID_E;
    unsigned short* wk_b  = wq_b + WQ_E;
    unsigned short* kn_ws = wk_b + WK_E;

    cvt_bf16_kernel<<<2048, 256, 0, stream>>>(hid, hid_b, (int)(HID_E / 8));
    cvt_bf16_kernel<<<512, 256, 0, stream>>>(Wq, wq_b, (int)(WQ_E / 8));
    cvt_bf16_kernel<<<256, 256, 0, stream>>>(Wk, wk_b, (int)(WK_E / 8));

    kproj_bf16<<<dim3(NH, S_TOK / 128), dim3(256), 0, stream>>>(hid_b, wk_b, knw, kn_ws);
    qscore_bf16<<<dim3(NH * NG, S_TOK / 128), dim3(256), 0, stream>>>(hid_b, wq_b, bq, qnw, bb, kb, kn_ws, out);
}

// Round 8
// 787.537 us; speedup vs baseline: 2.4320x; 1.1474x over previous
//
#include <hip/hip_runtime.h>

#define S_TOK 32768
#define DIN   2048
#define NH    8
#define NG    4
#define DH    128
#define NSINK 16
#define BK    64

typedef float        f32x4 __attribute__((ext_vector_type(4)));
typedef short        s16x8 __attribute__((ext_vector_type(8)));
typedef unsigned int u32x4 __attribute__((ext_vector_type(4)));

#define UR _Pragma("unroll")

__device__ __forceinline__ unsigned short f2bf(float f) {
    unsigned int u = __builtin_bit_cast(unsigned int, f);
    u = (u + 0x7fffu + ((u >> 16) & 1u)) >> 16;
    return (unsigned short)u;
}
__device__ __forceinline__ float bf2f(unsigned short h) {
    unsigned int u = ((unsigned int)h) << 16;
    return __builtin_bit_cast(float, u);
}
__device__ __forceinline__ unsigned int pack2(float lo, float hi) {
    return (unsigned int)f2bf(lo) | ((unsigned int)f2bf(hi) << 16);
}

// ---------------- fp32 -> bf16 pre-conversion
__global__ __launch_bounds__(256) void cvt_bf16_kernel(const float* __restrict__ in,
                                                       unsigned short* __restrict__ out,
                                                       int n8)
{
    int i = blockIdx.x * 256 + threadIdx.x;
    const int stride = gridDim.x * 256;
    for (; i < n8; i += stride) {
        const float* p = in + (size_t)i * 8;
        float4 a = *(const float4*)p;
        float4 b = *(const float4*)(p + 4);
        u32x4 v;
        v.x = pack2(a.x, a.y); v.y = pack2(a.z, a.w);
        v.z = pack2(b.x, b.y); v.w = pack2(b.z, b.w);
        *(u32x4*)(out + (size_t)i * 8) = v;
    }
}

// ---------------- Kernel A (R7-proven): k = RMSNorm(hid @ Wk^T)*k_norm_w -> kn_ws bf16 [S][1024]
__global__ __launch_bounds__(256) void kproj_bf16(const unsigned short* __restrict__ hid,
                                                  const unsigned short* __restrict__ Wk,
                                                  const float* __restrict__ knw,
                                                  unsigned short* __restrict__ kn_ws)
{
    __shared__ alignas(16) unsigned short smem[16896];
    __shared__ float rms_l[128];
    __shared__ float wsm[128];
    unsigned short (*qs)[132] = (unsigned short(*)[132])smem;

    const int tid = threadIdx.x, lane = tid & 63, wv = tid >> 6;
    const int wm = wv >> 1, wn = wv & 1;
    const int h = blockIdx.x, m0 = blockIdx.y * 128;
    if (tid < 128) wsm[tid] = knw[tid];

    const int lr = lane >> 3;
    const int lc = (((lane & 7) ^ lr) * 8);
    const int av0 = (wv * 32 + 0  + lr) * DIN + lc;
    const int av1 = (wv * 32 + 8  + lr) * DIN + lc;
    const int av2 = (wv * 32 + 16 + lr) * DIN + lc;
    const int av3 = (wv * 32 + 24 + lr) * DIN + lc;
    const int rA0 = (wm * 64 + (lane & 15)) * BK + ((lane >> 4) ^ (lane & 7)) * 8;
    const int rA1 = (wm * 64 + (lane & 15)) * BK + (((lane >> 4) + 4) ^ (lane & 7)) * 8;
    const int rB0 = (wn * 64 + (lane & 15)) * BK + ((lane >> 4) ^ (lane & 7)) * 8;
    const int rB1 = (wn * 64 + (lane & 15)) * BK + (((lane >> 4) + 4) ^ (lane & 7)) * 8;

    const unsigned short* aP = hid + (size_t)m0 * DIN;
    const unsigned short* bP = Wk + (size_t)h * DH * DIN;

    f32x4 acc[4][4];
    UR for (int m = 0; m < 4; ++m)
        UR for (int n = 0; n < 4; ++n)
            acc[m][n] = f32x4{0.f, 0.f, 0.f, 0.f};

    for (int kt = 0; kt < DIN; kt += BK) {
        UR for (int i = 0; i < 4; ++i) {
            const int ao = (i == 0) ? av0 : (i == 1) ? av1 : (i == 2) ? av2 : av3;
            __builtin_amdgcn_global_load_lds(
                (const __attribute__((address_space(1))) unsigned int*)(aP + ao),
                (__attribute__((address_space(3))) unsigned int*)(smem + (wv * 32 + i * 8) * BK), 16, 0, 0);
            __builtin_amdgcn_global_load_lds(
                (const __attribute__((address_space(1))) unsigned int*)(bP + ao),
                (__attribute__((address_space(3))) unsigned int*)(smem + 8192 + (wv * 32 + i * 8) * BK), 16, 0, 0);
        }
        __syncthreads();
        UR for (int kk = 0; kk < 2; ++kk) {
            const int sA = (kk ? rA1 : rA0);
            const int sB = 8192 + (kk ? rB1 : rB0);
            s16x8 af[4], bfr[4];
            UR for (int m = 0; m < 4; ++m) af[m] = *(const s16x8*)&smem[sA + m * 1024];
            UR for (int n = 0; n < 4; ++n) bfr[n] = *(const s16x8*)&smem[sB + n * 1024];
            UR for (int m = 0; m < 4; ++m)
                UR for (int n = 0; n < 4; ++n)
                    acc[m][n] = __builtin_amdgcn_mfma_f32_16x16x32_bf16(af[m], bfr[n], acc[m][n], 0, 0, 0);
        }
        __syncthreads();
        aP += BK; bP += BK;
    }

    UR for (int m = 0; m < 4; ++m)
        UR for (int n = 0; n < 4; ++n)
            UR for (int r = 0; r < 4; ++r)
                qs[wm * 64 + m * 16 + (lane >> 4) * 4 + r][wn * 64 + n * 16 + (lane & 15)] = f2bf(acc[m][n][r]);
    __syncthreads();
    if (tid < 128) {
        const unsigned short* row = qs[tid];
        float s2 = 0.f;
        UR for (int dw = 0; dw < 64; ++dw) {
            unsigned int v = *(const unsigned int*)&row[dw * 2];
            float f0 = bf2f((unsigned short)(v & 0xffff));
            float f1 = bf2f((unsigned short)(v >> 16));
            s2 += f0 * f0 + f1 * f1;
        }
        rms_l[tid] = rsqrtf(s2 * (1.0f / 128.0f) + 1e-6f);
    }
    __syncthreads();
    const int rloc = tid >> 4, cb = (tid & 15) * 8;
    UR for (int pass = 0; pass < 8; ++pass) {
        const int r = pass * 16 + rloc;
        const float rq = rms_l[r];
        u32x4 v;
        float f0, f1;
        f0 = bf2f(qs[r][cb + 0]) * rq * wsm[cb + 0];
        f1 = bf2f(qs[r][cb + 1]) * rq * wsm[cb + 1];
        v.x = pack2(f0, f1);
        f0 = bf2f(qs[r][cb + 2]) * rq * wsm[cb + 2];
        f1 = bf2f(qs[r][cb + 3]) * rq * wsm[cb + 3];
        v.y = pack2(f0, f1);
        f0 = bf2f(qs[r][cb + 4]) * rq * wsm[cb + 4];
        f1 = bf2f(qs[r][cb + 5]) * rq * wsm[cb + 5];
        v.z = pack2(f0, f1);
        f0 = bf2f(qs[r][cb + 6]) * rq * wsm[cb + 6];
        f1 = bf2f(qs[r][cb + 7]) * rq * wsm[cb + 7];
        v.w = pack2(f0, f1);
        *(u32x4*)&kn_ws[(size_t)(m0 + r) * (NH * DH) + h * DH + cb] = v;
    }
}

// ---------------- Kernel B: 256x256-tile deep-pipelined q-proj + RMSNorm + MFMA sink gate
// LDS buffer (32768 elems each): A[256][64] at +0 (halves at 0/8192), B[256][64] at +16384.
// Granule slot s of row r stores global granule s^(r&7); read slot = g^(r&7).
// Schedule per K-tile: stage ALL of tile t+1 (8 global_load_lds) at tile start into the
// other buffer, 64 MFMA + 24 ds_read in one region, then ONE vmcnt(0)+s_barrier.
// The drain is issued a full tile (~900cy) after the loads -> latency hidden; strict
// double-buffering + the single end-of-tile barrier make stage-vs-read race-free.
__global__ __launch_bounds__(512, 2) void qscore_bf16(const unsigned short* __restrict__ hid,
                                                      const unsigned short* __restrict__ Wq,
                                                      const float* __restrict__ bq,
                                                      const float* __restrict__ qnw,
                                                      const float* __restrict__ bb,
                                                      const float* __restrict__ kbase,
                                                      const unsigned short* __restrict__ kn_ws,
                                                      float* __restrict__ out)
{
    __shared__ alignas(16) unsigned short smem[65536];      // 2 x 64KB staging; qsc aliases after loop
    __shared__ alignas(16) unsigned short kbn[NSINK][136];  // bf16(k_base * q_norm_w)
    __shared__ float rms_l[256];
    __shared__ float l_l[256];
    __shared__ float wsm[128];
    unsigned short (*qsc)[132] = (unsigned short(*)[132])smem;  // per-chunk q tile, epilogue alias

    const int tid = threadIdx.x, lane = tid & 63, wv = tid >> 6;
    const int wm = wv >> 2, wn = wv & 3;           // 2M x 4N wave grid; wave owns 128x64
    const int nt = blockIdx.x;                     // n-tile 0..15 (fast: shares A across L2)
    const int m0 = blockIdx.y * 256;
    const int n0 = nt * 256;
    const int h  = nt >> 1;                        // both chunks of this tile share one head

    if (tid < 128) wsm[tid] = qnw[tid];
    if (tid < 256) {
        const int ts = tid >> 4, d0 = (tid & 15) * 8;
        const float* src = kbase + ((size_t)h * NSINK + ts) * DH + d0;
        float4 x = *(const float4*)src;
        float4 y = *(const float4*)(src + 4);
        const float* w = qnw + d0;
        u32x4 v;
        v.x = pack2(x.x * w[0], x.y * w[1]);
        v.y = pack2(x.z * w[2], x.w * w[3]);
        v.z = pack2(y.x * w[4], y.y * w[5]);
        v.w = pack2(y.z * w[6], y.w * w[7]);
        *(u32x4*)&kbn[ts][d0] = v;
    }

    // staging source offset (per-thread): granule index = tid (j=0) / tid+512 (j=1)
    const int srow = tid >> 3;
    const int so0 = srow * DIN + (((tid & 7) ^ (srow & 7)) * 8);   // j=1 adds 64*DIN, lds +4096

    // fragment ds_read offsets (row&7 == lane&7 for all frags since frag rows are 16-aligned)
    const int l15 = lane & 15;
    const int slotA = ((lane >> 4) ^ (lane & 7)) * 8;
    const int aOff0 = (wm * 128 + l15) * 64 + slotA;
    const int aOff1 = aOff0 ^ 32;                  // kk=1: slot^4 -> elem offset ^32
    const int bOff0 = (wn * 64 + l15) * 64 + slotA;
    const int bOff1 = bOff0 ^ 32;

    const unsigned short* aStage = hid + (size_t)m0 * DIN;
    const unsigned short* bStage = Wq + (size_t)n0 * DIN;

    f32x4 acc[8][4];
    UR for (int m = 0; m < 8; ++m)
        UR for (int n = 0; n < 4; ++n)
            acc[m][n] = f32x4{0.f, 0.f, 0.f, 0.f};

    s16x8 aF[4][2], bF[4][2];

#define GL(LDSB, SRC)                                                                              \
    __builtin_amdgcn_global_load_lds(                                                              \
        (const __attribute__((address_space(1))) unsigned int*)((SRC) + so0),                      \
        (__attribute__((address_space(3))) unsigned int*)(smem + (LDSB) + tid * 8), 16, 0, 0);     \
    __builtin_amdgcn_global_load_lds(                                                              \
        (const __attribute__((address_space(1))) unsigned int*)((SRC) + so0 + 64 * DIN),           \
        (__attribute__((address_space(3))) unsigned int*)(smem + (LDSB) + 4096 + tid * 8), 16, 0, 0);

#define GLALL(BUFW)                                                                                \
    { GL((BUFW) + 0,     aStage)             GL((BUFW) + 8192,  aStage + 128 * DIN)                \
      GL((BUFW) + 16384, bStage)             GL((BUFW) + 24576, bStage + 128 * DIN) }

#define LDA(BUF, QH)                                                                               \
    { UR for (int i_ = 0; i_ < 4; ++i_) {                                                          \
        aF[i_][0] = *(const s16x8*)&smem[(BUF) + aOff0 + ((QH) * 4 + i_) * 1024];                  \
        aF[i_][1] = *(const s16x8*)&smem[(BUF) + aOff1 + ((QH) * 4 + i_) * 1024]; } }

#define LDB(BUF, NH2)                                                                              \
    { UR for (int j_ = 0; j_ < 2; ++j_) {                                                          \
        bF[(NH2) * 2 + j_][0] = *(const s16x8*)&smem[(BUF) + 16384 + bOff0 + ((NH2) * 2 + j_) * 1024]; \
        bF[(NH2) * 2 + j_][1] = *(const s16x8*)&smem[(BUF) + 16384 + bOff1 + ((NH2) * 2 + j_) * 1024]; } }

#define MFMAQ(MF0, NF0)                                                                            \
    { __builtin_amdgcn_s_setprio(1);                                                               \
      UR for (int i_ = 0; i_ < 4; ++i_)                                                            \
        UR for (int j_ = 0; j_ < 2; ++j_)                                                          \
          UR for (int k_ = 0; k_ < 2; ++k_)                                                        \
            acc[(MF0) + i_][(NF0) + j_] = __builtin_amdgcn_mfma_f32_16x16x32_bf16(                 \
                aF[i_][k_], bF[(NF0) + j_][k_], acc[(MF0) + i_][(NF0) + j_], 0, 0, 0);             \
      __builtin_amdgcn_s_setprio(0); }

#define TILE(BUFR, BUFW, DOSTAGE)                                                                  \
    {                                                                                              \
        LDA(BUFR, 0); LDB(BUFR, 0);                                                                \
        if (DOSTAGE) { GLALL(BUFW); aStage += BK; bStage += BK; }                                  \
        MFMAQ(0, 0);                                                                               \
        LDB(BUFR, 1);                                                                              \
        MFMAQ(0, 2);                                                                               \
        LDA(BUFR, 1);                                                                              \
        MFMAQ(4, 2);                                                                               \
        MFMAQ(4, 0);                                                                               \
        asm volatile("s_waitcnt vmcnt(0)" ::: "memory");                                           \
        asm volatile("s_barrier" ::: "memory");                                                    \
    }

    // prologue: stage tile 0 -> buf0, drain, barrier
    GLALL(0)
    aStage += BK; bStage += BK;
    asm volatile("s_waitcnt vmcnt(0)" ::: "memory");
    asm volatile("s_barrier" ::: "memory");

    for (int i = 0; i < 15; ++i) {
        TILE(0, 32768, 1);       // even tile: read buf0, stage next -> buf1
        TILE(32768, 0, 1);       // odd tile: read buf1, stage next -> buf0
    }
    TILE(0, 32768, 1);           // tile 30 (stages tile 31)
    TILE(32768, 0, 0);           // tile 31 (no staging)

#undef GL
#undef GLALL
#undef LDA
#undef LDB
#undef MFMAQ
#undef TILE

    // ---- epilogue: two chunk-rounds (chunk c = cols c*128..c*128+127 of the 256-wide tile)
    float bqv[4];
    UR for (int nf = 0; nf < 4; ++nf)
        bqv[nf] = bq[n0 + wn * 64 + nf * 16 + l15];

    for (int c = 0; c < 2; ++c) {
        if (((wv >> 1) & 1) == c) {
            UR for (int mf = 0; mf < 8; ++mf)
                UR for (int nf = 0; nf < 4; ++nf)
                    UR for (int r = 0; r < 4; ++r)
                        qsc[wm * 128 + mf * 16 + (lane >> 4) * 4 + r][(wv & 1) * 64 + nf * 16 + l15] =
                            f2bf(acc[mf][nf][r] + bqv[nf]);
        }
        __syncthreads();

        const float bvalc = 2.0f * bb[h * NG + ((nt * 2 + c) & 3)];
        // pass2: 2 threads per row; rms + k.q logit (k from L2-resident kn_ws)
        {
            const int r2 = tid >> 1, ch = (tid & 1) * 64;
            const unsigned short* qrow = &qsc[r2][ch];
            const unsigned short* kg = kn_ws + (size_t)(m0 + r2) * (NH * DH) + h * DH + ch;
            const float* wp = &wsm[ch];
            float s2 = 0.f, skq = 0.f;
            UR for (int i = 0; i < 8; ++i) {
                u32x4 kv = *(const u32x4*)(kg + i * 8);
                UR for (int j = 0; j < 4; ++j) {
                    unsigned int qv = *(const unsigned int*)&qrow[i * 8 + j * 2];
                    unsigned int kw = kv[j];
                    float q0 = bf2f((unsigned short)(qv & 0xffff));
                    float q1 = bf2f((unsigned short)(qv >> 16));
                    float k0 = bf2f((unsigned short)(kw & 0xffff));
                    float k1 = bf2f((unsigned short)(kw >> 16));
                    s2  += q0 * q0 + q1 * q1;
                    skq += q0 * k0 * wp[i * 8 + j * 2] + q1 * k1 * wp[i * 8 + j * 2 + 1];
                }
            }
            s2  += __shfl_xor(s2, 1);
            skq += __shfl_xor(skq, 1);
            if ((tid & 1) == 0) {
                const float rs = rsqrtf(s2 * (1.0f / 128.0f) + 1e-6f) * 0.08838834764831845f;
                rms_l[r2] = rs;
                l_l[r2]   = skq * rs + bvalc;
            }
        }
        __syncthreads();

        // pass3 (MFMA): sink logits; wave wv owns rows [wv*32, wv*32+32)
        {
            f32x4 sacc0 = f32x4{0.f, 0.f, 0.f, 0.f};
            f32x4 sacc1 = f32x4{0.f, 0.f, 0.f, 0.f};
            const int ar = wv * 32 + l15;
            const int kc = (lane >> 4) * 8;
            UR for (int ks = 0; ks < 4; ++ks) {
                s16x8 bf_ = *(const s16x8*)&kbn[l15][ks * 32 + kc];
                s16x8 a0  = *(const s16x8*)&qsc[ar][ks * 32 + kc];
                s16x8 a1  = *(const s16x8*)&qsc[ar + 16][ks * 32 + kc];
                sacc0 = __builtin_amdgcn_mfma_f32_16x16x32_bf16(a0, bf_, sacc0, 0, 0, 0);
                sacc1 = __builtin_amdgcn_mfma_f32_16x16x32_bf16(a1, bf_, sacc1, 0, 0, 0);
            }
            UR for (int mt = 0; mt < 2; ++mt) {
                f32x4 sa = mt ? sacc1 : sacc0;
                UR for (int r = 0; r < 4; ++r) {
                    const int row = wv * 32 + mt * 16 + (lane >> 4) * 4 + r;
                    float e = __expf(sa[r] * rms_l[row] - l_l[row]);
                    e += __shfl_xor(e, 1);
                    e += __shfl_xor(e, 2);
                    e += __shfl_xor(e, 4);
                    e += __shfl_xor(e, 8);
                    if (l15 == 0)
                        atomicAdd(&out[(size_t)h * S_TOK + m0 + row], 0.25f / (1.0f + e));
                }
            }
        }
        __syncthreads();   // before next round overwrites qsc
    }
}

extern "C" void kernel_launch(void* const* d_in, const int* in_sizes, int n_in,
                              void* d_out, int out_size, void* d_ws, size_t ws_size,
                              hipStream_t stream)
{
    const float* hid = (const float*)d_in[0];
    const float* Wq  = (const float*)d_in[1];
    const float* bq  = (const float*)d_in[2];
    const float* Wk  = (const float*)d_in[3];
    const float* qnw = (const float*)d_in[4];
    const float* knw = (const float*)d_in[5];
    const float* bb  = (const float*)d_in[6];
    const float* kb  = (const float*)d_in[7];
    float* out = (float*)d_out;

    (void)hipMemsetAsync(d_out, 0, (size_t)out_size * sizeof(float), stream);

    const size_t HID_E = (size_t)S_TOK * DIN;
    const size_t WQ_E  = (size_t)NH * NG * DH * DIN;
    const size_t WK_E  = (size_t)NH * DH * DIN;

    unsigned short* hid_b = (unsigned short*)d_ws;
    unsigned short* wq_b  = hid_b + HID_E;
    unsigned short* wk_b  = wq_b + WQ_E;
    unsigned short* kn_ws = wk_b + WK_E;

    cvt_bf16_kernel<<<2048, 256, 0, stream>>>(hid, hid_b, (int)(HID_E / 8));
    cvt_bf16_kernel<<<512, 256, 0, stream>>>(Wq, wq_b, (int)(WQ_E / 8));
    cvt_bf16_kernel<<<256, 256, 0, stream>>>(Wk, wk_b, (int)(WK_E / 8));

    kproj_bf16<<<dim3(NH, S_TOK / 128), dim3(256), 0, stream>>>(hid_b, wk_b, knw, kn_ws);
    qscore_bf16<<<dim3(NH * NG / 2, S_TOK / 256), dim3(512), 0, stream>>>(hid_b, wq_b, bq, qnw, bb, kb, kn_ws, out);
}